// Round 5
// baseline (183.474 us; speedup 1.0000x reference)
//
#include <hip/hip_runtime.h>
#include <math.h>

#define S_LEN 1024
#define NHEAD 8
#define BATCH 8
#define KDIM  64
#define HID   32
#define NT    2048
#define LOG2E 1.4426950408889634f
#define TRI(q) ((q) * ((q) + 1) / 2)
// key-order bit-shuffle: m=[nb1 nb0 q1 q0 r1 r0] -> key=[nb1 q1 q0 nb0 r1 r0]
#define PERM(m) (((m) & 0x20) | (((m) & 0x0C) << 1) | (((m) & 0x10) >> 2) | ((m) & 3))
// LDS column swizzle key per row (3 bits, conflict-free for K(perm) and V reads)
#define SWZ(row) (((((row) >> 3) & 1) << 2) | ((row) & 3))

typedef __attribute__((ext_vector_type(8))) short bf16x8;
typedef __attribute__((ext_vector_type(4))) float f32x4;
typedef unsigned short ushort_t;

__device__ inline ushort_t f2bf(float f) {
  union { float f; unsigned u; } v; v.f = f;
  unsigned u = v.u;
  return (ushort_t)((u + 0x7FFFu + ((u >> 16) & 1u)) >> 16);
}
__device__ inline float bf2f(ushort_t u) {
  union { unsigned x; float f; } v; v.x = ((unsigned)u) << 16; return v.f;
}
__device__ inline unsigned cvtpk_bf16(float lo, float hi) {
  unsigned r;
  asm("v_cvt_pk_bf16_f32 %0, %1, %2" : "=v"(r) : "v"(lo), "v"(hi));
  return r;
}

// async global->LDS 16B: lane's LDS dest = lds_base + lane*16 (wave-uniform base)
__device__ inline void gl_lds16(const ushort_t* g, ushort_t* l) {
  __builtin_amdgcn_global_load_lds(
      (const __attribute__((address_space(1))) unsigned int*)g,
      (__attribute__((address_space(3))) unsigned int*)l, 16, 0, 0);
}

// ---------------------------------------------------------------------------
// Kernel 1: prep = weights to_bf16 (blocks 0..1023) + fire_tables (1024..3079).
// src conversion is FUSED into the QKV GEMM (R4): prep no longer touches src,
// removing ~25 MB of HBM traffic and shrinking this serial stage ~5x.
// Q weights pre-scaled by (1/sqrt(KD)) * log2e and the FIRE bias table by
// log2e so attention softmax uses bare v_exp_f32 (exp2) with no per-value mul.
// ---------------------------------------------------------------------------
__global__ __launch_bounds__(256) void prep(
    const float* __restrict__ wq,
    const float* __restrict__ wk, const float* __restrict__ wv,
    const float* __restrict__ wo,
    ushort_t* __restrict__ wqb,
    ushort_t* __restrict__ wkb, ushort_t* __restrict__ wvb,
    ushort_t* __restrict__ wob,
    const float* __restrict__ c_raw, const float* __restrict__ Lp,
    const float* __restrict__ w1, const float* __restrict__ b1,
    const float* __restrict__ W2, const float* __restrict__ b2,
    const float* __restrict__ w3, const float* __restrict__ b3,
    float* __restrict__ num_g, float* __restrict__ rden_g,
    float* __restrict__ gtab_g) {
  __shared__ float h1s[8][33];
  const int bx = blockIdx.x;
  const int tid = threadIdx.x;
  if (bx < 1024) {
    const float* src; ushort_t* dst; int base; float scale = 1.0f;
    if (bx < 256)      { src = wq; dst = wqb; base = bx;       scale = 0.125f * LOG2E; }
    else if (bx < 512) { src = wk; dst = wkb; base = bx - 256; }
    else if (bx < 768) { src = wv; dst = wvb; base = bx - 512; }
    else               { src = wo; dst = wob; base = bx - 768; }
    const int i = (base * 256 + tid) * 4;
    float4 v = *(const float4*)&src[i];
    ushort4 o;
    o.x = f2bf(v.x * scale); o.y = f2bf(v.y * scale);
    o.z = f2bf(v.z * scale); o.w = f2bf(v.w * scale);
    *(ushort4*)&dst[i] = o;
  } else {
    const int idx = bx - 1024;
    const int h = idx / 257;
    const int xb = idx % 257;
    const float cr = c_raw[h];
    const float c = (cr > 20.f) ? cr : log1pf(expf(cr));
    const int gid = xb * 256 + tid;
    if (gid < S_LEN) {
      num_g[h * S_LEN + gid] = log1pf(c * (float)gid);
      rden_g[h * S_LEN + gid] = 1.0f / log1pf(c * fmaxf(Lp[h], (float)(gid + 1)));
    }
    const int pl = tid >> 5;             // point-local 0..7
    const int j = tid & 31;              // hidden dim
    const int pt = xb * 8 + pl;
    const float x = (float)pt * (1.0f / NT);
    float v = x * w1[h * HID + j] + b1[h * HID + j];
    h1s[pl][j] = 0.5f * v * (1.0f + erff(v * 0.70710678118f));
    __syncthreads();
    float sm = b2[h * HID + j];
    const float* w2r = W2 + ((size_t)(h * HID + j)) * HID;
    #pragma unroll
    for (int k = 0; k < HID; ++k) sm += w2r[k] * h1s[pl][k];
    float g = 0.5f * sm * (1.0f + erff(sm * 0.70710678118f));
    float y = w3[h * HID + j] * g;
    #pragma unroll
    for (int off = 1; off < 32; off <<= 1) y += __shfl_xor(y, off);
    if (j == 0 && pt <= NT) gtab_g[h * (NT + 1) + pt] = (y + b3[h]) * LOG2E;
  }
}

// ---------------------------------------------------------------------------
// GEMM tile body: C = A(Mx512) * W^T (512x512 bf16, NxK). 64x64 tile, 4 waves,
// BK=64, 2-phase double-buffered staging.
// AF32=true (QKV): A is the raw f32 src; staged via T14 split — issue f32
//   loads for tile t+1, compute tile t, then cvt_pk_bf16 + swizzled
//   ds_write_b128 into the other buffer (fuses the old prep src-conversion).
//   LDS layout identical to the gl_lds16 path (slot = chunk ^ (row&7)).
// AF32=false (out-proj): A is bf16 (Obb), staged via gl_lds16 as before.
// W always staged via gl_lds16 with source-side XOR swizzle.
// mode 0: f32 row-major Mx512. mode 1: bf16 scatter [b,h,s,kd].
// mode 2: V^T bf16 [b,h,kd,s] via LDS transpose.
// ---------------------------------------------------------------------------
template <bool AF32>
__device__ __forceinline__ void gemm_tile(
    ushort_t* sAB, const void* __restrict__ Ap, const ushort_t* __restrict__ Wp,
    void* __restrict__ outp, int mode, int m0, int n0, int tid) {
  const int lane = tid & 63, w = tid >> 6, quad = lane >> 4, l16 = lane & 15;
  f32x4 acc[4];
  #pragma unroll
  for (int nb = 0; nb < 4; ++nb) acc[nb] = (f32x4)0.0f;

  const int r8 = lane >> 3;          // row within 8-row staging group
  const int c8 = lane & 7;           // linear chunk (f32 path source / LDS slot base)
  const int gc = c8 ^ r8;            // swizzled source chunk (gl_lds16 paths)
  const int sw = l16 & 7;            // frag-read swizzle key

  float4 rA0[2], rA1[2];             // f32 A staging regs (2 j-groups x 8 floats)

  auto stageA_issue = [&](int kt) {
    if (AF32) {
      const float* Af = (const float*)Ap;
      {
        const float* p = &Af[(size_t)(m0 + w * 16 + r8) * 512 + kt + c8 * 8];
        rA0[0] = *(const float4*)p; rA0[1] = *(const float4*)(p + 4);
      }
      {
        const float* p = &Af[(size_t)(m0 + w * 16 + 8 + r8) * 512 + kt + c8 * 8];
        rA1[0] = *(const float4*)p; rA1[1] = *(const float4*)(p + 4);
      }
    }
  };
  auto stageA_write = [&](int buf) {      // AF32 only: cvt + swizzled ds_write
    ushort_t* sA = sAB + buf * 8192;
    #pragma unroll
    for (int j = 0; j < 2; ++j) {
      const int row = w * 16 + j * 8 + r8;
      float4 a = j ? rA1[0] : rA0[0];
      float4 b = j ? rA1[1] : rA0[1];
      union { bf16x8 v; unsigned u[4]; } pk8;
      pk8.u[0] = cvtpk_bf16(a.x, a.y);
      pk8.u[1] = cvtpk_bf16(a.z, a.w);
      pk8.u[2] = cvtpk_bf16(b.x, b.y);
      pk8.u[3] = cvtpk_bf16(b.z, b.w);
      *(bf16x8*)&sA[row * 64 + (c8 ^ r8) * 8] = pk8.v;
    }
  };
  auto stageA_lds = [&](int kt, int buf) {  // bf16 A via gl_lds16
    ushort_t* sA = sAB + buf * 8192;
    const ushort_t* Ab = (const ushort_t*)Ap;
    #pragma unroll
    for (int j = 0; j < 2; ++j) {
      const int row = w * 16 + j * 8 + r8;
      gl_lds16(&Ab[(size_t)(m0 + row) * 512 + kt + gc * 8], &sA[(w * 16 + j * 8) * 64]);
    }
  };
  auto stageW = [&](int kt, int buf) {
    ushort_t* sB = sAB + buf * 8192 + 4096;
    #pragma unroll
    for (int j = 0; j < 2; ++j) {
      const int row = w * 16 + j * 8 + r8;
      gl_lds16(&Wp[(size_t)(n0 + row) * 512 + kt + gc * 8], &sB[(w * 16 + j * 8) * 64]);
    }
  };

  // prologue: tile 0
  stageA_issue(0);
  stageW(0, 0);
  if (AF32) stageA_write(0); else stageA_lds(0, 0);
  __syncthreads();                       // tile 0 landed (barrier drains vmcnt)

  for (int kt8 = 0; kt8 < 8; ++kt8) {
    const int cur = kt8 & 1;
    if (kt8 < 7) {
      stageA_issue((kt8 + 1) * 64);              // f32 loads in flight over compute
      stageW((kt8 + 1) * 64, cur ^ 1);           // fire-and-forget
      if (!AF32) stageA_lds((kt8 + 1) * 64, cur ^ 1);
    }
    const ushort_t* sA = sAB + cur * 8192;
    const ushort_t* sB = sA + 4096;
    #pragma unroll
    for (int ks = 0; ks < 2; ++ks) {
      const int off = ((ks * 4 + quad) ^ sw) * 8;
      bf16x8 af = *(const bf16x8*)&sA[(w * 16 + l16) * 64 + off];
      #pragma unroll
      for (int nb = 0; nb < 4; ++nb) {
        bf16x8 bfr = *(const bf16x8*)&sB[(nb * 16 + l16) * 64 + off];
        acc[nb] = __builtin_amdgcn_mfma_f32_16x16x32_bf16(af, bfr, acc[nb], 0, 0, 0);
      }
    }
    if (AF32 && kt8 < 7) stageA_write(cur ^ 1);  // waits only the f32 A loads
    __syncthreads();   // drains vmcnt/lgkm (next tile landed) + protects buf reuse
  }

  if (mode == 2) {
    // V^T: acc -> LDS (XOR-swizzled [n][m]) -> coalesced [b,h,kd,s] stores
    // (loop ended with a barrier; sAB scratch is safe to overwrite)
    #pragma unroll
    for (int nb = 0; nb < 4; ++nb)
      #pragma unroll
      for (int r = 0; r < 4; ++r) {
        int nl = nb * 16 + l16;
        int ml = w * 16 + quad * 4 + r;
        sAB[nl * 64 + (((ml >> 3) ^ (nl & 7)) * 8) + (ml & 7)] = f2bf(acc[nb][r]);
      }
    __syncthreads();
    const int nl = tid >> 2, seg = tid & 3;
    const int ng = n0 + nl, hh = ng >> 6, kd = ng & 63;
    const int bb = m0 >> 10, sbase = m0 & 1023;
    ushort_t* vout = (ushort_t*)outp + (((size_t)(bb * NHEAD + hh)) * KDIM + kd) * S_LEN;
    #pragma unroll
    for (int c2 = 0; c2 < 2; ++c2) {
      int mc = seg * 2 + c2;
      bf16x8 vr = *(bf16x8*)&sAB[nl * 64 + ((mc ^ (nl & 7)) * 8)];
      *(bf16x8*)&vout[sbase + mc * 8] = vr;
    }
    return;
  }
  #pragma unroll
  for (int nb = 0; nb < 4; ++nb) {
    #pragma unroll
    for (int r = 0; r < 4; ++r) {
      int m = m0 + w * 16 + quad * 4 + r;
      int n = n0 + nb * 16 + l16;
      float v = acc[nb][r];
      if (mode == 1) {
        int bb = m >> 10, ss = m & 1023, hh = n >> 6, kd = n & 63;
        ((ushort_t*)outp)[(((size_t)(bb * NHEAD + hh)) * S_LEN + ss) * KDIM + kd] = f2bf(v);
      } else {
        ((float*)outp)[(size_t)m * 512 + n] = v;
      }
    }
  }
}

// ---------------------------------------------------------------------------
// Kernel 2/4: gemm_bias. Blocks < nGemm: 64x64 GEMM tiles. scatter=1 (QKV):
// A = raw f32 src (conversion fused); z = idx%3 fastest (L2 locality);
// tile = idx/3, m0=(tile&127)*64, n0=(tile>>7)*64.
// scatter=0 (out-proj): A = bf16 Obb; z=0, m0=(idx&127)*64, n0=(idx>>7)*64.
// Blocks >= nGemm: bias-pre (2 tiles per 256-thr block) in PERM fragment
// order with causal -inf baked in (values log2e-scaled via gtab).
// ---------------------------------------------------------------------------
__global__ __launch_bounds__(256) void gemm_bias(
    const float* __restrict__ Af32, const ushort_t* __restrict__ Abf,
    const ushort_t* __restrict__ W0, const ushort_t* __restrict__ W1,
    const ushort_t* __restrict__ W2w,
    void* __restrict__ out0, void* __restrict__ out1, void* __restrict__ out2,
    int scatter, int nGemm,
    const float* __restrict__ num_g, const float* __restrict__ rden_g,
    const float* __restrict__ gtab_g, ushort_t* __restrict__ biaspre) {
  __shared__ __align__(16) ushort_t sAB[16384];   // 32 KB (2-phase dbuf)
  const int tid = threadIdx.x;
  if ((int)blockIdx.x < nGemm) {
    int z, tile;
    if (scatter) { z = blockIdx.x % 3; tile = blockIdx.x / 3; }
    else         { z = 0;              tile = blockIdx.x; }
    const int m0 = (tile & 127) * 64;
    const int n0 = (tile >> 7) * 64;
    const ushort_t* Wp = (z == 0) ? W0 : (z == 1) ? W1 : W2w;
    void* outp = (z == 0) ? out0 : (z == 1) ? out1 : out2;
    if (scatter) {
      gemm_tile<true>(sAB, (const void*)Af32, Wp, outp, (z == 2) ? 2 : 1, m0, n0, tid);
    } else {
      gemm_tile<false>(sAB, (const void*)Abf, Wp, outp, 0, m0, n0, tid);
    }
  } else {
    const int idx = blockIdx.x - nGemm;      // 0..543
    const int h = idx / 68;
    const int pair = idx % 68;
    float* gtab_s = (float*)sAB;             // 2049 floats
    float* num_s = gtab_s + 2052;            // 1024 floats
    float* rden_s = num_s + 1024;            // [2][64]  (total ~12.9 KB < 32 KB)
    for (int i = tid; i <= NT; i += 256) gtab_s[i] = gtab_g[h * (NT + 1) + i];
    for (int i = tid; i < S_LEN; i += 256) num_s[i] = num_g[h * S_LEN + i];
    const int sub = tid >> 7, tid2 = tid & 127;
    const int tileIdx = pair * 2 + sub;
    int qt = 0;
    while (TRI(qt + 1) <= tileIdx) ++qt;
    const int t = tileIdx - TRI(qt);
    if (tid2 < 64) rden_s[sub * 64 + tid2] = rden_g[h * S_LEN + qt * 64 + tid2];
    __syncthreads();
    const int w = tid2 >> 6, lane = tid2 & 63, quad = lane >> 4, l16 = lane & 15;
    ushort_t vals[32];
    #pragma unroll
    for (int qg = 0; qg < 2; ++qg) {
      const int iloc = w * 32 + qg * 16 + l16;
      const int i = qt * 64 + iloc;
      const float rden = rden_s[sub * 64 + iloc];
      #pragma unroll
      for (int nb = 0; nb < 4; ++nb)
        #pragma unroll
        for (int r = 0; r < 4; ++r) {
          const int m = nb * 16 + quad * 4 + r;
          const int j = t * 64 + PERM(m);
          ushort_t out;
          if (j > i) {
            out = 0xFF80;  // bf16 -inf (causal)
          } else {
            const int d = i - j;
            float x = num_s[d] * rden;       // in [0,1)
            float tf = x * (float)NT;
            int it = (int)tf; it = it < (NT - 1) ? it : (NT - 1);
            float fr = tf - (float)it;
            float ga = gtab_s[it];
            out = f2bf(ga + (gtab_s[it + 1] - ga) * fr);
          }
          vals[qg * 16 + nb * 4 + r] = out;
        }
    }
    ushort_t* dst = &biaspre[((size_t)(h * 136 + tileIdx) * 128 + tid2) * 32];
    uint4 u[2];
    #pragma unroll
    for (int half = 0; half < 2; ++half) {
      #pragma unroll
      for (int v = 0; v < 8; ++v) ((ushort_t*)&u[0])[v] = vals[half * 16 + v];
      #pragma unroll
      for (int v = 0; v < 8; ++v) ((ushort_t*)&u[1])[v] = vals[half * 16 + 8 + v];
      *(uint4*)(dst + half * 16) = u[0];
      *(uint4*)(dst + half * 16 + 8) = u[1];
    }
  }
}

// ---------------------------------------------------------------------------
// Kernel 3: transposed MFMA causal flash attention. 1024 blocks x 128 thr
// (2 waves x 32 q-rows), one (qt, b, h) each. S^T = K.Q^T with PERM'd key
// order; P^T fragments for O^T = V^T.P^T register-local. K/V staged via
// global_load_lds with source-side XOR swizzle, 2-phase double-buffered.
// Softmax: exp2-folded + v_cvt_pk_bf16_f32 packing.
// ---------------------------------------------------------------------------
__global__ __launch_bounds__(128) void fire_attn_mfma(
    const ushort_t* __restrict__ Qg, const ushort_t* __restrict__ Kg,
    const ushort_t* __restrict__ Vtg, const ushort_t* __restrict__ biaspre,
    ushort_t* __restrict__ Ob) {
  __shared__ __align__(16) ushort_t Ks[2 * 64 * 64];   // [buf][64x64]
  __shared__ __align__(16) ushort_t Vt[2 * 64 * 64];
  const int tid = threadIdx.x;
  const int lane = tid & 63, w = tid >> 6, quad = lane >> 4, l16 = lane & 15;
  const int g = blockIdx.x >> 6;
  const int qt = (g < 8) ? (15 - g) : (g - 8);
  const int bh = blockIdx.x & 63, h = bh & 7, b = bh >> 3;

  // Q fragments (B-operand layout == A layout: [l16][quad*8+j]); Q pre-scaled
  // by (1/8)*log2e in prep.
  bf16x8 q[2][2];
  {
    const size_t qb = (size_t)bh * S_LEN + qt * 64 + w * 32;
    #pragma unroll
    for (int qg = 0; qg < 2; ++qg)
      #pragma unroll
      for (int ks = 0; ks < 2; ++ks)
        q[qg][ks] = *(const bf16x8*)&Qg[(qb + qg * 16 + l16) * KDIM + ks * 32 + quad * 8];
  }

  const size_t kb = (size_t)bh * S_LEN * KDIM;
  const ushort_t* bptr = &biaspre[((size_t)(h * 136 + TRI(qt)) * 128 + tid) * 32];
  const int srow8 = lane >> 3;   // staging row-within-group
  const int sc = lane & 7;       // staging chunk

  auto stageKV = [&](int t, int buf) {
    #pragma unroll
    for (int j = 0; j < 4; ++j) {
      const int row = (w * 4 + j) * 8 + srow8;
      const int cc = sc ^ SWZ(row);
      gl_lds16(&Kg[kb + (size_t)(t * 64 + row) * 64 + cc * 8],
               &Ks[buf * 4096 + (w * 4 + j) * 512]);
      gl_lds16(&Vtg[kb + (size_t)row * 1024 + t * 64 + cc * 8],
               &Vt[buf * 4096 + (w * 4 + j) * 512]);
    }
  };

  f32x4 o[2][4];
  float ll[2] = {0.f, 0.f};
  #pragma unroll
  for (int qg = 0; qg < 2; ++qg)
    #pragma unroll
    for (int nb = 0; nb < 4; ++nb) o[qg][nb] = (f32x4)0.0f;

  stageKV(0, 0);
  __syncthreads();                 // tile 0 landed
  for (int t = 0; t <= qt; ++t) {
    const int cur = t & 1;
    if (t < qt) stageKV(t + 1, cur ^ 1);      // issue-ahead into other buf
    const ushort_t* Kc = Ks + cur * 4096;
    const ushort_t* Vc = Vt + cur * 4096;

    // bias (fragment order, -inf baked, log2e-scaled); in flight during QK
    uint4 bb0 = ((const uint4*)(bptr + (size_t)t * 4096))[0];
    uint4 bb1 = ((const uint4*)(bptr + (size_t)t * 4096))[1];
    uint4 bb2 = ((const uint4*)(bptr + (size_t)t * 4096))[2];
    uint4 bb3 = ((const uint4*)(bptr + (size_t)t * 4096))[3];

    // ---- S^T = K . Q^T  (keys in PERM order on the m-dim)
    f32x4 s[2][4];
    #pragma unroll
    for (int qg = 0; qg < 2; ++qg)
      #pragma unroll
      for (int nb = 0; nb < 4; ++nb) s[qg][nb] = (f32x4)0.0f;
    #pragma unroll
    for (int ks = 0; ks < 2; ++ks) {
      #pragma unroll
      for (int nb = 0; nb < 4; ++nb) {
        const int rk = PERM(nb * 16 + l16);
        bf16x8 ak = *(const bf16x8*)&Kc[rk * 64 + (((ks * 4 + quad) ^ SWZ(rk)) * 8)];
        #pragma unroll
        for (int qg = 0; qg < 2; ++qg)
          s[qg][nb] = __builtin_amdgcn_mfma_f32_16x16x32_bf16(ak, q[qg][ks], s[qg][nb], 0, 0, 0);
      }
    }

    // ---- P = exp2(S + bias); no-max softmax (|logit| small); l per-lane.
    unsigned pk[2][4][2];
    #pragma unroll
    for (int qg = 0; qg < 2; ++qg) {
      #pragma unroll
      for (int nb = 0; nb < 4; ++nb) {
        const int v = qg * 16 + nb * 4;
        const uint4& bq = (v < 8) ? bb0 : (v < 16) ? bb1 : (v < 24) ? bb2 : bb3;
        const ushort_t* bu = (const ushort_t*)&bq;
        float p0 = __builtin_amdgcn_exp2f(s[qg][nb][0] + bf2f(bu[(v + 0) & 7]));
        float p1 = __builtin_amdgcn_exp2f(s[qg][nb][1] + bf2f(bu[(v + 1) & 7]));
        float p2 = __builtin_amdgcn_exp2f(s[qg][nb][2] + bf2f(bu[(v + 2) & 7]));
        float p3 = __builtin_amdgcn_exp2f(s[qg][nb][3] + bf2f(bu[(v + 3) & 7]));
        ll[qg] += (p0 + p1) + (p2 + p3);
        pk[qg][nb][0] = cvtpk_bf16(p0, p1);
        pk[qg][nb][1] = cvtpk_bf16(p2, p3);
      }
    }

    // ---- O^T += V^T . P^T   (P^T B-frags are register-local thanks to PERM)
    #pragma unroll
    for (int ks = 0; ks < 2; ++ks) {
      bf16x8 pf[2];
      #pragma unroll
      for (int qg = 0; qg < 2; ++qg) {
        union { bf16x8 v; unsigned u[4]; } pkx;
        pkx.u[0] = pk[qg][2 * ks][0];
        pkx.u[1] = pk[qg][2 * ks][1];
        pkx.u[2] = pk[qg][2 * ks + 1][0];
        pkx.u[3] = pk[qg][2 * ks + 1][1];
        pf[qg] = pkx.v;
      }
      #pragma unroll
      for (int nb = 0; nb < 4; ++nb) {
        const int rv = nb * 16 + l16;
        bf16x8 av = *(const bf16x8*)&Vc[rv * 64 + (((ks * 4 + quad) ^ SWZ(rv)) * 8)];
        #pragma unroll
        for (int qg = 0; qg < 2; ++qg)
          o[qg][nb] = __builtin_amdgcn_mfma_f32_16x16x32_bf16(av, pf[qg], o[qg][nb], 0, 0, 0);
      }
    }
    __syncthreads();   // drains vmcnt (tile t+1 landed) + protects buf reuse
  }

  // ---- epilogue: l reduced across quads (qrow = qg*16+l16 for all lane vals)
  #pragma unroll
  for (int qg = 0; qg < 2; ++qg) {
    float rs = ll[qg];
    rs += __shfl_xor(rs, 16);
    rs += __shfl_xor(rs, 32);
    const float rl = 1.0f / rs;
    const size_t ob = ((size_t)(b * S_LEN + qt * 64 + w * 32 + qg * 16 + l16)) * 512 + h * KDIM;
    #pragma unroll
    for (int nb = 0; nb < 4; ++nb) {
      ushort4 ov;
      ov.x = f2bf(o[qg][nb][0] * rl);
      ov.y = f2bf(o[qg][nb][1] * rl);
      ov.z = f2bf(o[qg][nb][2] * rl);
      ov.w = f2bf(o[qg][nb][3] * rl);
      *(ushort4*)&Ob[ob + nb * 16 + quad * 4] = ov;
    }
  }
}

// ---------------------------------------------------------------------------
extern "C" void kernel_launch(void* const* d_in, const int* in_sizes, int n_in,
                              void* d_out, int out_size, void* d_ws, size_t ws_size,
                              hipStream_t stream) {
  const float* src   = (const float*)d_in[0];
  const float* Wq    = (const float*)d_in[1];
  const float* Wk    = (const float*)d_in[2];
  const float* Wv    = (const float*)d_in[3];
  const float* c_raw = (const float*)d_in[4];
  const float* Lp    = (const float*)d_in[5];
  const float* w1    = (const float*)d_in[6];
  const float* b1    = (const float*)d_in[7];
  const float* W2    = (const float*)d_in[8];
  const float* b2    = (const float*)d_in[9];
  const float* w3    = (const float*)d_in[10];
  const float* b3    = (const float*)d_in[11];
  const float* Wo    = (const float*)d_in[12];
  float* outp = (float*)d_out;

  const size_t W_E   = 262144;    // 512*512
  const size_t QKV_E = 4194304;   // 64*1024*64
  ushort_t* Wqb  = (ushort_t*)d_ws;
  ushort_t* Wkb  = Wqb + W_E;
  ushort_t* Wvb  = Wkb + W_E;
  ushort_t* Wob  = Wvb + W_E;
  ushort_t* Qb   = Wob + W_E;
  ushort_t* Kb   = Qb + QKV_E;
  ushort_t* Vtb  = Kb + QKV_E;    // V transposed: [b,h,kd,s]
  ushort_t* Obb  = Vtb + QKV_E;
  ushort_t* biaspre = Obb + QKV_E;                 // 8*136*128*32 ushorts
  float* numb  = (float*)(biaspre + (size_t)NHEAD * 136 * 128 * 32);
  float* rdenb = numb + NHEAD * S_LEN;
  float* gtabb = rdenb + NHEAD * S_LEN;

  // 1) weights bf16 convert + FIRE tables (src conversion fused into QKV GEMM)
  hipLaunchKernelGGL(prep, dim3(3080), dim3(256), 0, stream,
                     Wq, Wk, Wv, Wo, Wqb, Wkb, Wvb, Wob,
                     c_raw, Lp, w1, b1, W2, b2, w3, b3, numb, rdenb, gtabb);
  // 2) QKV GEMM (3072 blocks, 64x64 tiles, f32-A fused convert) + bias-pre
  hipLaunchKernelGGL(gemm_bias, dim3(3616), dim3(256), 0, stream,
                     src, (const ushort_t*)nullptr, Wqb, Wkb, Wvb,
                     (void*)Qb, (void*)Kb, (void*)Vtb,
                     1, 3072, numb, rdenb, gtabb, biaspre);
  // 3) attention
  hipLaunchKernelGGL(fire_attn_mfma, dim3(1024), dim3(128), 0, stream,
                     Qb, Kb, Vtb, biaspre, Obb);
  // 4) output projection (f32 out, 1024 blocks of 64x64)
  hipLaunchKernelGGL(gemm_bias, dim3(1024), dim3(256), 0, stream,
                     (const float*)nullptr, Obb, Wob, Wob, Wob,
                     (void*)outp, (void*)outp, (void*)outp,
                     0, 1024, numb, rdenb, gtabb, biaspre);
}

// Round 6
// 170.213 us; speedup vs baseline: 1.0779x; 1.0779x over previous
//
#include <hip/hip_runtime.h>
#include <math.h>

#define S_LEN 1024
#define NHEAD 8
#define BATCH 8
#define KDIM  64
#define HID   32
#define NT    2048
#define LOG2E 1.4426950408889634f
#define TRI(q) ((q) * ((q) + 1) / 2)
// key-order bit-shuffle: m=[nb1 nb0 q1 q0 r1 r0] -> key=[nb1 q1 q0 nb0 r1 r0]
#define PERM(m) (((m) & 0x20) | (((m) & 0x0C) << 1) | (((m) & 0x10) >> 2) | ((m) & 3))
// LDS column swizzle key per row (3 bits, conflict-free for K(perm) and V reads)
#define SWZ(row) (((((row) >> 3) & 1) << 2) | ((row) & 3))

typedef __attribute__((ext_vector_type(8))) short bf16x8;
typedef __attribute__((ext_vector_type(4))) float f32x4;
typedef unsigned short ushort_t;

__device__ inline ushort_t f2bf(float f) {
  union { float f; unsigned u; } v; v.f = f;
  unsigned u = v.u;
  return (ushort_t)((u + 0x7FFFu + ((u >> 16) & 1u)) >> 16);
}
__device__ inline float bf2f(ushort_t u) {
  union { unsigned x; float f; } v; v.x = ((unsigned)u) << 16; return v.f;
}
__device__ inline unsigned cvtpk_bf16(float lo, float hi) {
  unsigned r;
  asm("v_cvt_pk_bf16_f32 %0, %1, %2" : "=v"(r) : "v"(lo), "v"(hi));
  return r;
}

// async global->LDS 16B: lane's LDS dest = lds_base + lane*16 (wave-uniform base)
__device__ inline void gl_lds16(const ushort_t* g, ushort_t* l) {
  __builtin_amdgcn_global_load_lds(
      (const __attribute__((address_space(1))) unsigned int*)g,
      (__attribute__((address_space(3))) unsigned int*)l, 16, 0, 0);
}

// ---------------------------------------------------------------------------
// Kernel 1: prep = to_bf16 (blocks 0..5119) + fire_tables (blocks 5120..7175).
// (R4's src-fusion reverted: it doubled A-side fetch bytes and regressed.)
// Q weights pre-scaled by (1/sqrt(KD)) * log2e and the FIRE bias table by
// log2e so attention softmax uses bare v_exp_f32 (exp2) with no per-value mul.
// ---------------------------------------------------------------------------
__global__ __launch_bounds__(256) void prep(
    const float* __restrict__ s, const float* __restrict__ wq,
    const float* __restrict__ wk, const float* __restrict__ wv,
    const float* __restrict__ wo,
    ushort_t* __restrict__ sb, ushort_t* __restrict__ wqb,
    ushort_t* __restrict__ wkb, ushort_t* __restrict__ wvb,
    ushort_t* __restrict__ wob,
    const float* __restrict__ c_raw, const float* __restrict__ Lp,
    const float* __restrict__ w1, const float* __restrict__ b1,
    const float* __restrict__ W2, const float* __restrict__ b2,
    const float* __restrict__ w3, const float* __restrict__ b3,
    float* __restrict__ num_g, float* __restrict__ rden_g,
    float* __restrict__ gtab_g) {
  __shared__ float h1s[8][33];
  const int bx = blockIdx.x;
  const int tid = threadIdx.x;
  if (bx < 5120) {
    const float* src; ushort_t* dst; int base; float scale = 1.0f;
    if (bx < 4096)      { src = s;  dst = sb;  base = bx; }
    else if (bx < 4352) { src = wq; dst = wqb; base = bx - 4096; scale = 0.125f * LOG2E; }
    else if (bx < 4608) { src = wk; dst = wkb; base = bx - 4352; }
    else if (bx < 4864) { src = wv; dst = wvb; base = bx - 4608; }
    else                { src = wo; dst = wob; base = bx - 4864; }
    const int i = (base * 256 + tid) * 4;
    float4 v = *(const float4*)&src[i];
    ushort4 o;
    o.x = f2bf(v.x * scale); o.y = f2bf(v.y * scale);
    o.z = f2bf(v.z * scale); o.w = f2bf(v.w * scale);
    *(ushort4*)&dst[i] = o;
  } else {
    const int idx = bx - 5120;
    const int h = idx / 257;
    const int xb = idx % 257;
    const float cr = c_raw[h];
    const float c = (cr > 20.f) ? cr : log1pf(expf(cr));
    const int gid = xb * 256 + tid;
    if (gid < S_LEN) {
      num_g[h * S_LEN + gid] = log1pf(c * (float)gid);
      rden_g[h * S_LEN + gid] = 1.0f / log1pf(c * fmaxf(Lp[h], (float)(gid + 1)));
    }
    const int pl = tid >> 5;             // point-local 0..7
    const int j = tid & 31;              // hidden dim
    const int pt = xb * 8 + pl;
    const float x = (float)pt * (1.0f / NT);
    float v = x * w1[h * HID + j] + b1[h * HID + j];
    h1s[pl][j] = 0.5f * v * (1.0f + erff(v * 0.70710678118f));
    __syncthreads();
    float sm = b2[h * HID + j];
    const float* w2r = W2 + ((size_t)(h * HID + j)) * HID;
    #pragma unroll
    for (int k = 0; k < HID; ++k) sm += w2r[k] * h1s[pl][k];
    float g = 0.5f * sm * (1.0f + erff(sm * 0.70710678118f));
    float y = w3[h * HID + j] * g;
    #pragma unroll
    for (int off = 1; off < 32; off <<= 1) y += __shfl_xor(y, off);
    if (j == 0 && pt <= NT) gtab_g[h * (NT + 1) + pt] = (y + b3[h]) * LOG2E;
  }
}

// ---------------------------------------------------------------------------
// GEMM tile body: C = A(Mx512 bf16) * W^T (512x512 bf16, NxK). 64x64 tile,
// 4 waves (wave w = rows w*16..w*16+16 x all 64 cols), BK=64, 2-phase
// double-buffered global_load_lds staging (stage kt+1 before computing kt,
// one vmcnt-draining barrier per K-step). LDS 32 KB: [buf][A 8KB | B 8KB].
// mode 0: f32 row-major Mx512. mode 1: bf16 scatter [b,h,s,kd].
// mode 2: V^T bf16 [b,h,kd,s] via LDS transpose.
// ---------------------------------------------------------------------------
__device__ __forceinline__ void gemm_tile(
    ushort_t* sAB, const ushort_t* __restrict__ A, const ushort_t* __restrict__ Wp,
    void* __restrict__ outp, int mode, int m0, int n0, int tid) {
  const int lane = tid & 63, w = tid >> 6, quad = lane >> 4, l16 = lane & 15;
  f32x4 acc[4];
  #pragma unroll
  for (int nb = 0; nb < 4; ++nb) acc[nb] = (f32x4)0.0f;

  const int r8 = lane >> 3;          // row within 8-row staging group
  const int gc = (lane & 7) ^ r8;    // swizzled source chunk for this lane
  const int sw = l16 & 7;            // frag-read swizzle key

  auto stage = [&](int kt, int buf) {
    ushort_t* sA = sAB + buf * 8192;
    ushort_t* sB = sA + 4096;
    #pragma unroll
    for (int j = 0; j < 2; ++j) {
      const int row = w * 16 + j * 8 + r8;
      gl_lds16(&A[(size_t)(m0 + row) * 512 + kt + gc * 8], &sA[(w * 16 + j * 8) * 64]);
      gl_lds16(&Wp[(size_t)(n0 + row) * 512 + kt + gc * 8], &sB[(w * 16 + j * 8) * 64]);
    }
  };

  stage(0, 0);
  __syncthreads();                       // tile 0 landed
  for (int kt8 = 0; kt8 < 8; ++kt8) {
    const int cur = kt8 & 1;
    if (kt8 < 7) stage((kt8 + 1) * 64, cur ^ 1);   // issue-ahead into other buf
    const ushort_t* sA = sAB + cur * 8192;
    const ushort_t* sB = sA + 4096;
    #pragma unroll
    for (int ks = 0; ks < 2; ++ks) {
      const int off = ((ks * 4 + quad) ^ sw) * 8;
      bf16x8 af = *(const bf16x8*)&sA[(w * 16 + l16) * 64 + off];
      #pragma unroll
      for (int nb = 0; nb < 4; ++nb) {
        bf16x8 bfr = *(const bf16x8*)&sB[(nb * 16 + l16) * 64 + off];
        acc[nb] = __builtin_amdgcn_mfma_f32_16x16x32_bf16(af, bfr, acc[nb], 0, 0, 0);
      }
    }
    __syncthreads();   // drains vmcnt (next tile landed) + protects buf reuse
  }

  if (mode == 2) {
    // V^T: acc -> LDS (XOR-swizzled [n][m]) -> coalesced [b,h,kd,s] stores
    // (loop ended with a barrier; sAB scratch is safe to overwrite)
    #pragma unroll
    for (int nb = 0; nb < 4; ++nb)
      #pragma unroll
      for (int r = 0; r < 4; ++r) {
        int nl = nb * 16 + l16;
        int ml = w * 16 + quad * 4 + r;
        sAB[nl * 64 + (((ml >> 3) ^ (nl & 7)) * 8) + (ml & 7)] = f2bf(acc[nb][r]);
      }
    __syncthreads();
    const int nl = tid >> 2, seg = tid & 3;
    const int ng = n0 + nl, hh = ng >> 6, kd = ng & 63;
    const int bb = m0 >> 10, sbase = m0 & 1023;
    ushort_t* vout = (ushort_t*)outp + (((size_t)(bb * NHEAD + hh)) * KDIM + kd) * S_LEN;
    #pragma unroll
    for (int c2 = 0; c2 < 2; ++c2) {
      int mc = seg * 2 + c2;
      bf16x8 vr = *(bf16x8*)&sAB[nl * 64 + ((mc ^ (nl & 7)) * 8)];
      *(bf16x8*)&vout[sbase + mc * 8] = vr;
    }
    return;
  }
  #pragma unroll
  for (int nb = 0; nb < 4; ++nb) {
    #pragma unroll
    for (int r = 0; r < 4; ++r) {
      int m = m0 + w * 16 + quad * 4 + r;
      int n = n0 + nb * 16 + l16;
      float v = acc[nb][r];
      if (mode == 1) {
        int bb = m >> 10, ss = m & 1023, hh = n >> 6, kd = n & 63;
        ((ushort_t*)outp)[(((size_t)(bb * NHEAD + hh)) * S_LEN + ss) * KDIM + kd] = f2bf(v);
      } else {
        ((float*)outp)[(size_t)m * 512 + n] = v;
      }
    }
  }
}

// ---------------------------------------------------------------------------
// Kernel 2/4: gemm_bias. Blocks < nGemm: 64x64 GEMM tiles, N-FASTEST tile
// order (R6): n0=(tile&7)*64, m0=(tile>>3)*64 — the 24 (QKV: 3z x 8n) /
// 8 (out-proj) blocks sharing one A-strip are dispatch-adjacent, so each
// A-strip is fetched from HBM once instead of once per n0-wave (R5 PMC:
// m-fastest order re-fetched A 8x = 147 MB FETCH on the f32 path).
// scatter=1 (QKV): z = idx%3 fastest. scatter=0 (out-proj): z=0.
// Blocks >= nGemm: bias-pre (2 tiles per 256-thr block) in PERM fragment
// order with causal -inf baked in (values log2e-scaled via gtab).
// ---------------------------------------------------------------------------
__global__ __launch_bounds__(256) void gemm_bias(
    const ushort_t* __restrict__ A,
    const ushort_t* __restrict__ W0, const ushort_t* __restrict__ W1,
    const ushort_t* __restrict__ W2w,
    void* __restrict__ out0, void* __restrict__ out1, void* __restrict__ out2,
    int scatter, int nGemm,
    const float* __restrict__ num_g, const float* __restrict__ rden_g,
    const float* __restrict__ gtab_g, ushort_t* __restrict__ biaspre) {
  __shared__ __align__(16) ushort_t sAB[16384];   // 32 KB (2-phase dbuf)
  const int tid = threadIdx.x;
  if ((int)blockIdx.x < nGemm) {
    int z, tile;
    if (scatter) { z = blockIdx.x % 3; tile = blockIdx.x / 3; }
    else         { z = 0;              tile = blockIdx.x; }
    const int n0 = (tile & 7) * 64;     // n-fastest (A-strip reuse in L2)
    const int m0 = (tile >> 3) * 64;
    const ushort_t* Wp = (z == 0) ? W0 : (z == 1) ? W1 : W2w;
    void* outp = (z == 0) ? out0 : (z == 1) ? out1 : out2;
    const int mode = scatter ? ((z == 2) ? 2 : 1) : 0;
    gemm_tile(sAB, A, Wp, outp, mode, m0, n0, tid);
  } else {
    const int idx = blockIdx.x - nGemm;      // 0..543
    const int h = idx / 68;
    const int pair = idx % 68;
    float* gtab_s = (float*)sAB;             // 2049 floats
    float* num_s = gtab_s + 2052;            // 1024 floats
    float* rden_s = num_s + 1024;            // [2][64]  (total ~12.9 KB < 32 KB)
    for (int i = tid; i <= NT; i += 256) gtab_s[i] = gtab_g[h * (NT + 1) + i];
    for (int i = tid; i < S_LEN; i += 256) num_s[i] = num_g[h * S_LEN + i];
    const int sub = tid >> 7, tid2 = tid & 127;
    const int tileIdx = pair * 2 + sub;
    int qt = 0;
    while (TRI(qt + 1) <= tileIdx) ++qt;
    const int t = tileIdx - TRI(qt);
    if (tid2 < 64) rden_s[sub * 64 + tid2] = rden_g[h * S_LEN + qt * 64 + tid2];
    __syncthreads();
    const int w = tid2 >> 6, lane = tid2 & 63, quad = lane >> 4, l16 = lane & 15;
    ushort_t vals[32];
    #pragma unroll
    for (int qg = 0; qg < 2; ++qg) {
      const int iloc = w * 32 + qg * 16 + l16;
      const int i = qt * 64 + iloc;
      const float rden = rden_s[sub * 64 + iloc];
      #pragma unroll
      for (int nb = 0; nb < 4; ++nb)
        #pragma unroll
        for (int r = 0; r < 4; ++r) {
          const int m = nb * 16 + quad * 4 + r;
          const int j = t * 64 + PERM(m);
          ushort_t out;
          if (j > i) {
            out = 0xFF80;  // bf16 -inf (causal)
          } else {
            const int d = i - j;
            float x = num_s[d] * rden;       // in [0,1)
            float tf = x * (float)NT;
            int it = (int)tf; it = it < (NT - 1) ? it : (NT - 1);
            float fr = tf - (float)it;
            float ga = gtab_s[it];
            out = f2bf(ga + (gtab_s[it + 1] - ga) * fr);
          }
          vals[qg * 16 + nb * 4 + r] = out;
        }
    }
    ushort_t* dst = &biaspre[((size_t)(h * 136 + tileIdx) * 128 + tid2) * 32];
    uint4 u[2];
    #pragma unroll
    for (int half = 0; half < 2; ++half) {
      #pragma unroll
      for (int v = 0; v < 8; ++v) ((ushort_t*)&u[0])[v] = vals[half * 16 + v];
      #pragma unroll
      for (int v = 0; v < 8; ++v) ((ushort_t*)&u[1])[v] = vals[half * 16 + 8 + v];
      *(uint4*)(dst + half * 16) = u[0];
      *(uint4*)(dst + half * 16 + 8) = u[1];
    }
  }
}

// ---------------------------------------------------------------------------
// Kernel 3: transposed MFMA causal flash attention. 1024 blocks x 128 thr
// (2 waves x 32 q-rows), one (qt, b, h) each. S^T = K.Q^T with PERM'd key
// order; P^T fragments for O^T = V^T.P^T register-local. K/V staged via
// global_load_lds with source-side XOR swizzle, 2-phase double-buffered.
// Softmax: exp2-folded + v_cvt_pk_bf16_f32 packing.
// ---------------------------------------------------------------------------
__global__ __launch_bounds__(128) void fire_attn_mfma(
    const ushort_t* __restrict__ Qg, const ushort_t* __restrict__ Kg,
    const ushort_t* __restrict__ Vtg, const ushort_t* __restrict__ biaspre,
    ushort_t* __restrict__ Ob) {
  __shared__ __align__(16) ushort_t Ks[2 * 64 * 64];   // [buf][64x64]
  __shared__ __align__(16) ushort_t Vt[2 * 64 * 64];
  const int tid = threadIdx.x;
  const int lane = tid & 63, w = tid >> 6, quad = lane >> 4, l16 = lane & 15;
  const int g = blockIdx.x >> 6;
  const int qt = (g < 8) ? (15 - g) : (g - 8);
  const int bh = blockIdx.x & 63, h = bh & 7, b = bh >> 3;

  // Q fragments (B-operand layout == A layout: [l16][quad*8+j]); Q pre-scaled
  // by (1/8)*log2e in prep.
  bf16x8 q[2][2];
  {
    const size_t qb = (size_t)bh * S_LEN + qt * 64 + w * 32;
    #pragma unroll
    for (int qg = 0; qg < 2; ++qg)
      #pragma unroll
      for (int ks = 0; ks < 2; ++ks)
        q[qg][ks] = *(const bf16x8*)&Qg[(qb + qg * 16 + l16) * KDIM + ks * 32 + quad * 8];
  }

  const size_t kb = (size_t)bh * S_LEN * KDIM;
  const ushort_t* bptr = &biaspre[((size_t)(h * 136 + TRI(qt)) * 128 + tid) * 32];
  const int srow8 = lane >> 3;   // staging row-within-group
  const int sc = lane & 7;       // staging chunk

  auto stageKV = [&](int t, int buf) {
    #pragma unroll
    for (int j = 0; j < 4; ++j) {
      const int row = (w * 4 + j) * 8 + srow8;
      const int cc = sc ^ SWZ(row);
      gl_lds16(&Kg[kb + (size_t)(t * 64 + row) * 64 + cc * 8],
               &Ks[buf * 4096 + (w * 4 + j) * 512]);
      gl_lds16(&Vtg[kb + (size_t)row * 1024 + t * 64 + cc * 8],
               &Vt[buf * 4096 + (w * 4 + j) * 512]);
    }
  };

  f32x4 o[2][4];
  float ll[2] = {0.f, 0.f};
  #pragma unroll
  for (int qg = 0; qg < 2; ++qg)
    #pragma unroll
    for (int nb = 0; nb < 4; ++nb) o[qg][nb] = (f32x4)0.0f;

  stageKV(0, 0);
  __syncthreads();                 // tile 0 landed
  for (int t = 0; t <= qt; ++t) {
    const int cur = t & 1;
    if (t < qt) stageKV(t + 1, cur ^ 1);      // issue-ahead into other buf
    const ushort_t* Kc = Ks + cur * 4096;
    const ushort_t* Vc = Vt + cur * 4096;

    // bias (fragment order, -inf baked, log2e-scaled); in flight during QK
    uint4 bb0 = ((const uint4*)(bptr + (size_t)t * 4096))[0];
    uint4 bb1 = ((const uint4*)(bptr + (size_t)t * 4096))[1];
    uint4 bb2 = ((const uint4*)(bptr + (size_t)t * 4096))[2];
    uint4 bb3 = ((const uint4*)(bptr + (size_t)t * 4096))[3];

    // ---- S^T = K . Q^T  (keys in PERM order on the m-dim)
    f32x4 s[2][4];
    #pragma unroll
    for (int qg = 0; qg < 2; ++qg)
      #pragma unroll
      for (int nb = 0; nb < 4; ++nb) s[qg][nb] = (f32x4)0.0f;
    #pragma unroll
    for (int ks = 0; ks < 2; ++ks) {
      #pragma unroll
      for (int nb = 0; nb < 4; ++nb) {
        const int rk = PERM(nb * 16 + l16);
        bf16x8 ak = *(const bf16x8*)&Kc[rk * 64 + (((ks * 4 + quad) ^ SWZ(rk)) * 8)];
        #pragma unroll
        for (int qg = 0; qg < 2; ++qg)
          s[qg][nb] = __builtin_amdgcn_mfma_f32_16x16x32_bf16(ak, q[qg][ks], s[qg][nb], 0, 0, 0);
      }
    }

    // ---- P = exp2(S + bias); no-max softmax (|logit| small); l per-lane.
    unsigned pk[2][4][2];
    #pragma unroll
    for (int qg = 0; qg < 2; ++qg) {
      #pragma unroll
      for (int nb = 0; nb < 4; ++nb) {
        const int v = qg * 16 + nb * 4;
        const uint4& bq = (v < 8) ? bb0 : (v < 16) ? bb1 : (v < 24) ? bb2 : bb3;
        const ushort_t* bu = (const ushort_t*)&bq;
        float p0 = __builtin_amdgcn_exp2f(s[qg][nb][0] + bf2f(bu[(v + 0) & 7]));
        float p1 = __builtin_amdgcn_exp2f(s[qg][nb][1] + bf2f(bu[(v + 1) & 7]));
        float p2 = __builtin_amdgcn_exp2f(s[qg][nb][2] + bf2f(bu[(v + 2) & 7]));
        float p3 = __builtin_amdgcn_exp2f(s[qg][nb][3] + bf2f(bu[(v + 3) & 7]));
        ll[qg] += (p0 + p1) + (p2 + p3);
        pk[qg][nb][0] = cvtpk_bf16(p0, p1);
        pk[qg][nb][1] = cvtpk_bf16(p2, p3);
      }
    }

    // ---- O^T += V^T . P^T   (P^T B-frags are register-local thanks to PERM)
    #pragma unroll
    for (int ks = 0; ks < 2; ++ks) {
      bf16x8 pf[2];
      #pragma unroll
      for (int qg = 0; qg < 2; ++qg) {
        union { bf16x8 v; unsigned u[4]; } pkx;
        pkx.u[0] = pk[qg][2 * ks][0];
        pkx.u[1] = pk[qg][2 * ks][1];
        pkx.u[2] = pk[qg][2 * ks + 1][0];
        pkx.u[3] = pk[qg][2 * ks + 1][1];
        pf[qg] = pkx.v;
      }
      #pragma unroll
      for (int nb = 0; nb < 4; ++nb) {
        const int rv = nb * 16 + l16;
        bf16x8 av = *(const bf16x8*)&Vc[rv * 64 + (((ks * 4 + quad) ^ SWZ(rv)) * 8)];
        #pragma unroll
        for (int qg = 0; qg < 2; ++qg)
          o[qg][nb] = __builtin_amdgcn_mfma_f32_16x16x32_bf16(av, pf[qg], o[qg][nb], 0, 0, 0);
      }
    }
    __syncthreads();   // drains vmcnt (tile t+1 landed) + protects buf reuse
  }

  // ---- epilogue: l reduced across quads (qrow = qg*16+l16 for all lane vals)
  #pragma unroll
  for (int qg = 0; qg < 2; ++qg) {
    float rs = ll[qg];
    rs += __shfl_xor(rs, 16);
    rs += __shfl_xor(rs, 32);
    const float rl = 1.0f / rs;
    const size_t ob = ((size_t)(b * S_LEN + qt * 64 + w * 32 + qg * 16 + l16)) * 512 + h * KDIM;
    #pragma unroll
    for (int nb = 0; nb < 4; ++nb) {
      ushort4 ov;
      ov.x = f2bf(o[qg][nb][0] * rl);
      ov.y = f2bf(o[qg][nb][1] * rl);
      ov.z = f2bf(o[qg][nb][2] * rl);
      ov.w = f2bf(o[qg][nb][3] * rl);
      *(ushort4*)&Ob[ob + nb * 16 + quad * 4] = ov;
    }
  }
}

// ---------------------------------------------------------------------------
extern "C" void kernel_launch(void* const* d_in, const int* in_sizes, int n_in,
                              void* d_out, int out_size, void* d_ws, size_t ws_size,
                              hipStream_t stream) {
  const float* src   = (const float*)d_in[0];
  const float* Wq    = (const float*)d_in[1];
  const float* Wk    = (const float*)d_in[2];
  const float* Wv    = (const float*)d_in[3];
  const float* c_raw = (const float*)d_in[4];
  const float* Lp    = (const float*)d_in[5];
  const float* w1    = (const float*)d_in[6];
  const float* b1    = (const float*)d_in[7];
  const float* W2    = (const float*)d_in[8];
  const float* b2    = (const float*)d_in[9];
  const float* w3    = (const float*)d_in[10];
  const float* b3    = (const float*)d_in[11];
  const float* Wo    = (const float*)d_in[12];
  float* outp = (float*)d_out;

  const size_t SRC_E = 4194304;   // 8*1024*512
  const size_t W_E   = 262144;    // 512*512
  const size_t QKV_E = 4194304;   // 64*1024*64
  ushort_t* srcb = (ushort_t*)d_ws;
  ushort_t* Wqb  = srcb + SRC_E;
  ushort_t* Wkb  = Wqb + W_E;
  ushort_t* Wvb  = Wkb + W_E;
  ushort_t* Wob  = Wvb + W_E;
  ushort_t* Qb   = Wob + W_E;
  ushort_t* Kb   = Qb + QKV_E;
  ushort_t* Vtb  = Kb + QKV_E;    // V transposed: [b,h,kd,s]
  ushort_t* Obb  = Vtb + QKV_E;
  ushort_t* biaspre = Obb + QKV_E;                 // 8*136*128*32 ushorts
  float* numb  = (float*)(biaspre + (size_t)NHEAD * 136 * 128 * 32);
  float* rdenb = numb + NHEAD * S_LEN;
  float* gtabb = rdenb + NHEAD * S_LEN;

  // 1) bf16 convert + FIRE tables (independent, merged)
  hipLaunchKernelGGL(prep, dim3(7176), dim3(256), 0, stream,
                     src, Wq, Wk, Wv, Wo, srcb, Wqb, Wkb, Wvb, Wob,
                     c_raw, Lp, w1, b1, W2, b2, w3, b3, numb, rdenb, gtabb);
  // 2) QKV GEMM (3072 blocks, 64x64 tiles, n-fastest) + bias-pre (544 blocks)
  hipLaunchKernelGGL(gemm_bias, dim3(3616), dim3(256), 0, stream,
                     srcb, Wqb, Wkb, Wvb, (void*)Qb, (void*)Kb, (void*)Vtb,
                     1, 3072, numb, rdenb, gtabb, biaspre);
  // 3) attention
  hipLaunchKernelGGL(fire_attn_mfma, dim3(1024), dim3(128), 0, stream,
                     Qb, Kb, Vtb, biaspre, Obb);
  // 4) output projection (f32 out, 1024 blocks of 64x64, n-fastest)
  hipLaunchKernelGGL(gemm_bias, dim3(1024), dim3(256), 0, stream,
                     Obb, Wob, Wob, Wob, (void*)outp, (void*)outp, (void*)outp,
                     0, 1024, numb, rdenb, gtabb, biaspre);
}

// Round 7
// 160.484 us; speedup vs baseline: 1.1433x; 1.0606x over previous
//
#include <hip/hip_runtime.h>
#include <math.h>

#define S_LEN 1024
#define NHEAD 8
#define BATCH 8
#define KDIM  64
#define HID   32
#define NT    2048
#define LOG2E 1.4426950408889634f
#define TRI(q) ((q) * ((q) + 1) / 2)
// key-order bit-shuffle: m=[nb1 nb0 q1 q0 r1 r0] -> key=[nb1 q1 q0 nb0 r1 r0]
#define PERM(m) (((m) & 0x20) | (((m) & 0x0C) << 1) | (((m) & 0x10) >> 2) | ((m) & 3))
// LDS column swizzle key per row (3 bits, conflict-free for K(perm) and V reads)
#define SWZ(row) (((((row) >> 3) & 1) << 2) | ((row) & 3))

typedef __attribute__((ext_vector_type(8))) short bf16x8;
typedef __attribute__((ext_vector_type(4))) float f32x4;
typedef unsigned short ushort_t;

__device__ inline ushort_t f2bf(float f) {
  union { float f; unsigned u; } v; v.f = f;
  unsigned u = v.u;
  return (ushort_t)((u + 0x7FFFu + ((u >> 16) & 1u)) >> 16);
}
__device__ inline float bf2f(ushort_t u) {
  union { unsigned x; float f; } v; v.x = ((unsigned)u) << 16; return v.f;
}
__device__ inline unsigned cvtpk_bf16(float lo, float hi) {
  unsigned r;
  asm("v_cvt_pk_bf16_f32 %0, %1, %2" : "=v"(r) : "v"(lo), "v"(hi));
  return r;
}

// async global->LDS 16B: lane's LDS dest = lds_base + lane*16 (wave-uniform base)
__device__ inline void gl_lds16(const ushort_t* g, ushort_t* l) {
  __builtin_amdgcn_global_load_lds(
      (const __attribute__((address_space(1))) unsigned int*)g,
      (__attribute__((address_space(3))) unsigned int*)l, 16, 0, 0);
}

// ---------------------------------------------------------------------------
// Kernel 1: prep = to_bf16 (blocks 0..5119) + fire_tables (blocks 5120..7175).
// Q weights pre-scaled by (1/sqrt(KD)) * log2e and the FIRE bias table by
// log2e so attention softmax uses bare v_exp_f32 (exp2) with no per-value mul.
// ---------------------------------------------------------------------------
__global__ __launch_bounds__(256) void prep(
    const float* __restrict__ s, const float* __restrict__ wq,
    const float* __restrict__ wk, const float* __restrict__ wv,
    const float* __restrict__ wo,
    ushort_t* __restrict__ sb, ushort_t* __restrict__ wqb,
    ushort_t* __restrict__ wkb, ushort_t* __restrict__ wvb,
    ushort_t* __restrict__ wob,
    const float* __restrict__ c_raw, const float* __restrict__ Lp,
    const float* __restrict__ w1, const float* __restrict__ b1,
    const float* __restrict__ W2, const float* __restrict__ b2,
    const float* __restrict__ w3, const float* __restrict__ b3,
    float* __restrict__ num_g, float* __restrict__ rden_g,
    float* __restrict__ gtab_g) {
  __shared__ float h1s[8][33];
  const int bx = blockIdx.x;
  const int tid = threadIdx.x;
  if (bx < 5120) {
    const float* src; ushort_t* dst; int base; float scale = 1.0f;
    if (bx < 4096)      { src = s;  dst = sb;  base = bx; }
    else if (bx < 4352) { src = wq; dst = wqb; base = bx - 4096; scale = 0.125f * LOG2E; }
    else if (bx < 4608) { src = wk; dst = wkb; base = bx - 4352; }
    else if (bx < 4864) { src = wv; dst = wvb; base = bx - 4608; }
    else                { src = wo; dst = wob; base = bx - 4864; }
    const int i = (base * 256 + tid) * 4;
    float4 v = *(const float4*)&src[i];
    ushort4 o;
    o.x = f2bf(v.x * scale); o.y = f2bf(v.y * scale);
    o.z = f2bf(v.z * scale); o.w = f2bf(v.w * scale);
    *(ushort4*)&dst[i] = o;
  } else {
    const int idx = bx - 5120;
    const int h = idx / 257;
    const int xb = idx % 257;
    const float cr = c_raw[h];
    const float c = (cr > 20.f) ? cr : log1pf(expf(cr));
    const int gid = xb * 256 + tid;
    if (gid < S_LEN) {
      num_g[h * S_LEN + gid] = log1pf(c * (float)gid);
      rden_g[h * S_LEN + gid] = 1.0f / log1pf(c * fmaxf(Lp[h], (float)(gid + 1)));
    }
    const int pl = tid >> 5;             // point-local 0..7
    const int j = tid & 31;              // hidden dim
    const int pt = xb * 8 + pl;
    const float x = (float)pt * (1.0f / NT);
    float v = x * w1[h * HID + j] + b1[h * HID + j];
    h1s[pl][j] = 0.5f * v * (1.0f + erff(v * 0.70710678118f));
    __syncthreads();
    float sm = b2[h * HID + j];
    const float* w2r = W2 + ((size_t)(h * HID + j)) * HID;
    #pragma unroll
    for (int k = 0; k < HID; ++k) sm += w2r[k] * h1s[pl][k];
    float g = 0.5f * sm * (1.0f + erff(sm * 0.70710678118f));
    float y = w3[h * HID + j] * g;
    #pragma unroll
    for (int off = 1; off < 32; off <<= 1) y += __shfl_xor(y, off);
    if (j == 0 && pt <= NT) gtab_g[h * (NT + 1) + pt] = (y + b3[h]) * LOG2E;
  }
}

// ---------------------------------------------------------------------------
// GEMM tile body: C = A(Mx512 bf16) * W^T (512x512 bf16, NxK). 64x64 tile,
// 4 waves, BK=64, single-buffer global_load_lds staging (R2 best-measured
// config; dbuf/128-tile/n-fastest all neutral in R1/R3/R6).
// mode 0: f32 row-major Mx512. mode 1: bf16 scatter [b,h,s,kd].
// mode 2: V^T bf16 [b,h,kd,s] via LDS transpose.
// ---------------------------------------------------------------------------
__device__ __forceinline__ void gemm_tile(
    ushort_t* sAB, const ushort_t* __restrict__ A, const ushort_t* __restrict__ Wp,
    void* __restrict__ outp, int mode, int m0, int n0, int tid) {
  ushort_t* sA = sAB;            // 64x64
  ushort_t* sB = sAB + 4096;
  const int lane = tid & 63, w = tid >> 6, quad = lane >> 4, l16 = lane & 15;
  f32x4 acc[4];
  #pragma unroll
  for (int nb = 0; nb < 4; ++nb) acc[nb] = (f32x4)0.0f;

  const int r8 = lane >> 3;          // row within 8-row staging group
  const int gc = (lane & 7) ^ r8;    // swizzled source chunk for this lane
  const int sw = l16 & 7;            // frag-read swizzle key

  for (int kt = 0; kt < 512; kt += 64) {
    __syncthreads();
    #pragma unroll
    for (int j = 0; j < 2; ++j) {
      const int row = w * 16 + j * 8 + r8;
      gl_lds16(&A[(size_t)(m0 + row) * 512 + kt + gc * 8], &sA[(w * 16 + j * 8) * 64]);
      gl_lds16(&Wp[(size_t)(n0 + row) * 512 + kt + gc * 8], &sB[(w * 16 + j * 8) * 64]);
    }
    __syncthreads();
    #pragma unroll
    for (int ks = 0; ks < 2; ++ks) {
      const int off = ((ks * 4 + quad) ^ sw) * 8;
      bf16x8 af = *(bf16x8*)&sA[(w * 16 + l16) * 64 + off];
      #pragma unroll
      for (int nb = 0; nb < 4; ++nb) {
        bf16x8 bfr = *(bf16x8*)&sB[(nb * 16 + l16) * 64 + off];
        acc[nb] = __builtin_amdgcn_mfma_f32_16x16x32_bf16(af, bfr, acc[nb], 0, 0, 0);
      }
    }
  }

  if (mode == 2) {
    // V^T: acc -> LDS (XOR-swizzled [n][m]) -> coalesced [b,h,kd,s] stores
    __syncthreads();
    #pragma unroll
    for (int nb = 0; nb < 4; ++nb)
      #pragma unroll
      for (int r = 0; r < 4; ++r) {
        int nl = nb * 16 + l16;
        int ml = w * 16 + quad * 4 + r;
        sAB[nl * 64 + (((ml >> 3) ^ (nl & 7)) * 8) + (ml & 7)] = f2bf(acc[nb][r]);
      }
    __syncthreads();
    const int nl = tid >> 2, seg = tid & 3;
    const int ng = n0 + nl, hh = ng >> 6, kd = ng & 63;
    const int bb = m0 >> 10, sbase = m0 & 1023;
    ushort_t* vout = (ushort_t*)outp + (((size_t)(bb * NHEAD + hh)) * KDIM + kd) * S_LEN;
    #pragma unroll
    for (int c2 = 0; c2 < 2; ++c2) {
      int mc = seg * 2 + c2;
      bf16x8 vr = *(bf16x8*)&sAB[nl * 64 + ((mc ^ (nl & 7)) * 8)];
      *(bf16x8*)&vout[sbase + mc * 8] = vr;
    }
    return;
  }
  #pragma unroll
  for (int nb = 0; nb < 4; ++nb) {
    #pragma unroll
    for (int r = 0; r < 4; ++r) {
      int m = m0 + w * 16 + quad * 4 + r;
      int n = n0 + nb * 16 + l16;
      float v = acc[nb][r];
      if (mode == 1) {
        int bb = m >> 10, ss = m & 1023, hh = n >> 6, kd = n & 63;
        ((ushort_t*)outp)[(((size_t)(bb * NHEAD + hh)) * S_LEN + ss) * KDIM + kd] = f2bf(v);
      } else {
        ((float*)outp)[(size_t)m * 512 + n] = v;
      }
    }
  }
}

// ---------------------------------------------------------------------------
// Kernel 2/4: gemm_bias. Blocks < nGemm: 64x64 GEMM tiles. scatter=1 (QKV):
// z = idx%3 fastest; tile = idx/3, m0=(tile&127)*64, n0=(tile>>7)*64.
// scatter=0 (out-proj): z=0. Blocks >= nGemm: bias-pre (2 tiles per block)
// in PERM fragment order with causal -inf baked in (log2e-scaled via gtab).
// ---------------------------------------------------------------------------
__global__ __launch_bounds__(256) void gemm_bias(
    const ushort_t* __restrict__ A,
    const ushort_t* __restrict__ W0, const ushort_t* __restrict__ W1,
    const ushort_t* __restrict__ W2w,
    void* __restrict__ out0, void* __restrict__ out1, void* __restrict__ out2,
    int scatter, int nGemm,
    const float* __restrict__ num_g, const float* __restrict__ rden_g,
    const float* __restrict__ gtab_g, ushort_t* __restrict__ biaspre) {
  __shared__ __align__(16) ushort_t sAB[8192];   // 16 KB
  const int tid = threadIdx.x;
  if ((int)blockIdx.x < nGemm) {
    int z, tile;
    if (scatter) { z = blockIdx.x % 3; tile = blockIdx.x / 3; }
    else         { z = 0;              tile = blockIdx.x; }
    const int m0 = (tile & 127) * 64;
    const int n0 = (tile >> 7) * 64;
    const ushort_t* Wp = (z == 0) ? W0 : (z == 1) ? W1 : W2w;
    void* outp = (z == 0) ? out0 : (z == 1) ? out1 : out2;
    const int mode = scatter ? ((z == 2) ? 2 : 1) : 0;
    gemm_tile(sAB, A, Wp, outp, mode, m0, n0, tid);
  } else {
    const int idx = blockIdx.x - nGemm;      // 0..543
    const int h = idx / 68;
    const int pair = idx % 68;
    float* gtab_s = (float*)sAB;             // 2049 floats
    float* num_s = gtab_s + 2052;            // 1024 floats
    float* rden_s = num_s + 1024;            // [2][64]  (total ~12.9 KB < 16 KB)
    for (int i = tid; i <= NT; i += 256) gtab_s[i] = gtab_g[h * (NT + 1) + i];
    for (int i = tid; i < S_LEN; i += 256) num_s[i] = num_g[h * S_LEN + i];
    const int sub = tid >> 7, tid2 = tid & 127;
    const int tileIdx = pair * 2 + sub;
    int qt = 0;
    while (TRI(qt + 1) <= tileIdx) ++qt;
    const int t = tileIdx - TRI(qt);
    if (tid2 < 64) rden_s[sub * 64 + tid2] = rden_g[h * S_LEN + qt * 64 + tid2];
    __syncthreads();
    const int w = tid2 >> 6, lane = tid2 & 63, quad = lane >> 4, l16 = lane & 15;
    ushort_t vals[32];
    #pragma unroll
    for (int qg = 0; qg < 2; ++qg) {
      const int iloc = w * 32 + qg * 16 + l16;
      const int i = qt * 64 + iloc;
      const float rden = rden_s[sub * 64 + iloc];
      #pragma unroll
      for (int nb = 0; nb < 4; ++nb)
        #pragma unroll
        for (int r = 0; r < 4; ++r) {
          const int m = nb * 16 + quad * 4 + r;
          const int j = t * 64 + PERM(m);
          ushort_t out;
          if (j > i) {
            out = 0xFF80;  // bf16 -inf (causal)
          } else {
            const int d = i - j;
            float x = num_s[d] * rden;       // in [0,1)
            float tf = x * (float)NT;
            int it = (int)tf; it = it < (NT - 1) ? it : (NT - 1);
            float fr = tf - (float)it;
            float ga = gtab_s[it];
            out = f2bf(ga + (gtab_s[it + 1] - ga) * fr);
          }
          vals[qg * 16 + nb * 4 + r] = out;
        }
    }
    ushort_t* dst = &biaspre[((size_t)(h * 136 + tileIdx) * 128 + tid2) * 32];
    uint4 u[2];
    #pragma unroll
    for (int half = 0; half < 2; ++half) {
      #pragma unroll
      for (int v = 0; v < 8; ++v) ((ushort_t*)&u[0])[v] = vals[half * 16 + v];
      #pragma unroll
      for (int v = 0; v < 8; ++v) ((ushort_t*)&u[1])[v] = vals[half * 16 + 8 + v];
      *(uint4*)(dst + half * 16) = u[0];
      *(uint4*)(dst + half * 16 + 8) = u[1];
    }
  }
}

// ---------------------------------------------------------------------------
// Kernel 3: transposed MFMA causal flash attention, SPLIT-KV (R7).
// 1024 blocks x 256 thr = 4 waves: wave-pair 0 (waves 0-1) handles KV tiles
// [0, hA), pair 1 (waves 2-3) handles [hA, qt], hA = ceil((qt+1)/2). Each
// pair has its own single-buffered 16 KB K/V LDS; partial (o, l) combined
// in-block via LDS at the end. Waves/SIMD: 2 -> 4 (attacks the latency-bound
// serial chain that R2/R3 proved is neither VALU- nor memory-limited).
// S^T = K.Q^T with PERM'd key order; P^T fragments register-local.
// Softmax: exp2-folded + v_cvt_pk_bf16_f32 packing.
// ---------------------------------------------------------------------------
__global__ __launch_bounds__(256) void fire_attn_mfma(
    const ushort_t* __restrict__ Qg, const ushort_t* __restrict__ Kg,
    const ushort_t* __restrict__ Vtg, const ushort_t* __restrict__ biaspre,
    ushort_t* __restrict__ Ob) {
  __shared__ __align__(16) ushort_t sKV[16384];  // K: pair*4096, V: 8192+pair*4096
  const int tid = threadIdx.x;
  const int lane = tid & 63, w = tid >> 6;
  const int pair = w >> 1, wq = w & 1;           // pair 0/1; wave-within-pair
  const int quad = lane >> 4, l16 = lane & 15;
  const int g = blockIdx.x >> 6;
  const int qt = (g < 8) ? (15 - g) : (g - 8);
  const int bh = blockIdx.x & 63, h = bh & 7, b = bh >> 3;
  const int tid2 = wq * 64 + lane;               // 0..127 within pair

  // Q fragments (B-operand layout == A layout); Q pre-scaled (1/8)*log2e.
  // Both pairs load the same 64 q-rows (wq gives the 32-row half).
  bf16x8 q[2][2];
  {
    const size_t qb = (size_t)bh * S_LEN + qt * 64 + wq * 32;
    #pragma unroll
    for (int qg = 0; qg < 2; ++qg)
      #pragma unroll
      for (int ks = 0; ks < 2; ++ks)
        q[qg][ks] = *(const bf16x8*)&Qg[(qb + qg * 16 + l16) * KDIM + ks * 32 + quad * 8];
  }

  const size_t kb = (size_t)bh * S_LEN * KDIM;
  const ushort_t* bptr = &biaspre[((size_t)(h * 136 + TRI(qt)) * 128 + tid2) * 32];
  const int srow8 = lane >> 3;   // staging row-within-group
  const int sc = lane & 7;       // staging chunk

  ushort_t* Kp = sKV + pair * 4096;
  ushort_t* Vp = sKV + 8192 + pair * 4096;

  auto stageKV = [&](int t) {
    #pragma unroll
    for (int j = 0; j < 4; ++j) {
      const int row = (wq * 4 + j) * 8 + srow8;
      const int cc = sc ^ SWZ(row);
      gl_lds16(&Kg[kb + (size_t)(t * 64 + row) * 64 + cc * 8], &Kp[(wq * 4 + j) * 512]);
      gl_lds16(&Vtg[kb + (size_t)row * 1024 + t * 64 + cc * 8], &Vp[(wq * 4 + j) * 512]);
    }
  };

  f32x4 o[2][4];
  float ll[2] = {0.f, 0.f};
  #pragma unroll
  for (int qg = 0; qg < 2; ++qg)
    #pragma unroll
    for (int nb = 0; nb < 4; ++nb) o[qg][nb] = (f32x4)0.0f;

  const int hA = (qt + 2) >> 1;        // pair 0 tile count (>= pair 1's)
  for (int it = 0; it < hA; ++it) {
    const int t = pair ? (hA + it) : it;
    const bool act = (!pair) || (t <= qt);   // wave-uniform predicate
    if (act) stageKV(t);
    __syncthreads();                   // staging landed (both pairs)
    if (act) {
      // bias (fragment order, -inf baked, log2e-scaled)
      uint4 bb0 = ((const uint4*)(bptr + (size_t)t * 4096))[0];
      uint4 bb1 = ((const uint4*)(bptr + (size_t)t * 4096))[1];
      uint4 bb2 = ((const uint4*)(bptr + (size_t)t * 4096))[2];
      uint4 bb3 = ((const uint4*)(bptr + (size_t)t * 4096))[3];

      // ---- S^T = K . Q^T  (keys in PERM order on the m-dim)
      f32x4 s[2][4];
      #pragma unroll
      for (int qg = 0; qg < 2; ++qg)
        #pragma unroll
        for (int nb = 0; nb < 4; ++nb) s[qg][nb] = (f32x4)0.0f;
      #pragma unroll
      for (int ks = 0; ks < 2; ++ks) {
        #pragma unroll
        for (int nb = 0; nb < 4; ++nb) {
          const int rk = PERM(nb * 16 + l16);
          bf16x8 ak = *(const bf16x8*)&Kp[rk * 64 + (((ks * 4 + quad) ^ SWZ(rk)) * 8)];
          #pragma unroll
          for (int qg = 0; qg < 2; ++qg)
            s[qg][nb] = __builtin_amdgcn_mfma_f32_16x16x32_bf16(ak, q[qg][ks], s[qg][nb], 0, 0, 0);
        }
      }

      // ---- P = exp2(S + bias); no-max softmax; l per-lane
      unsigned pk[2][4][2];
      #pragma unroll
      for (int qg = 0; qg < 2; ++qg) {
        #pragma unroll
        for (int nb = 0; nb < 4; ++nb) {
          const int v = qg * 16 + nb * 4;
          const uint4& bq = (v < 8) ? bb0 : (v < 16) ? bb1 : (v < 24) ? bb2 : bb3;
          const ushort_t* bu = (const ushort_t*)&bq;
          float p0 = __builtin_amdgcn_exp2f(s[qg][nb][0] + bf2f(bu[(v + 0) & 7]));
          float p1 = __builtin_amdgcn_exp2f(s[qg][nb][1] + bf2f(bu[(v + 1) & 7]));
          float p2 = __builtin_amdgcn_exp2f(s[qg][nb][2] + bf2f(bu[(v + 2) & 7]));
          float p3 = __builtin_amdgcn_exp2f(s[qg][nb][3] + bf2f(bu[(v + 3) & 7]));
          ll[qg] += (p0 + p1) + (p2 + p3);
          pk[qg][nb][0] = cvtpk_bf16(p0, p1);
          pk[qg][nb][1] = cvtpk_bf16(p2, p3);
        }
      }

      // ---- O^T += V^T . P^T (P^T B-frags register-local thanks to PERM)
      #pragma unroll
      for (int ks = 0; ks < 2; ++ks) {
        bf16x8 pf[2];
        #pragma unroll
        for (int qg = 0; qg < 2; ++qg) {
          union { bf16x8 v; unsigned u[4]; } pkx;
          pkx.u[0] = pk[qg][2 * ks][0];
          pkx.u[1] = pk[qg][2 * ks][1];
          pkx.u[2] = pk[qg][2 * ks + 1][0];
          pkx.u[3] = pk[qg][2 * ks + 1][1];
          pf[qg] = pkx.v;
        }
        #pragma unroll
        for (int nb = 0; nb < 4; ++nb) {
          const int rv = nb * 16 + l16;
          bf16x8 av = *(const bf16x8*)&Vp[rv * 64 + (((ks * 4 + quad) ^ SWZ(rv)) * 8)];
          #pragma unroll
          for (int qg = 0; qg < 2; ++qg)
            o[qg][nb] = __builtin_amdgcn_mfma_f32_16x16x32_bf16(av, pf[qg], o[qg][nb], 0, 0, 0);
        }
      }
    }
    __syncthreads();                   // reads done before buffer reuse
  }

  // ---- pair combine via LDS (34 floats/thread-slot; 2-way bank alias = free)
  float* cb = (float*)sKV;
  if (pair == 1) {
    float* my = cb + tid2 * 34;
    #pragma unroll
    for (int qg = 0; qg < 2; ++qg)
      #pragma unroll
      for (int nb = 0; nb < 4; ++nb)
        #pragma unroll
        for (int r = 0; r < 4; ++r) my[qg * 16 + nb * 4 + r] = o[qg][nb][r];
    my[32] = ll[0]; my[33] = ll[1];
  }
  __syncthreads();
  if (pair == 0) {
    const float* pb = cb + tid2 * 34;
    #pragma unroll
    for (int qg = 0; qg < 2; ++qg)
      #pragma unroll
      for (int nb = 0; nb < 4; ++nb)
        #pragma unroll
        for (int r = 0; r < 4; ++r) o[qg][nb][r] += pb[qg * 16 + nb * 4 + r];
    ll[0] += pb[32]; ll[1] += pb[33];

    // epilogue: l reduced across quads (qrow = qg*16+l16 for all lane vals)
    #pragma unroll
    for (int qg = 0; qg < 2; ++qg) {
      float rs = ll[qg];
      rs += __shfl_xor(rs, 16);
      rs += __shfl_xor(rs, 32);
      const float rl = 1.0f / rs;
      const size_t ob = ((size_t)(b * S_LEN + qt * 64 + wq * 32 + qg * 16 + l16)) * 512 + h * KDIM;
      #pragma unroll
      for (int nb = 0; nb < 4; ++nb) {
        ushort4 ov;
        ov.x = f2bf(o[qg][nb][0] * rl);
        ov.y = f2bf(o[qg][nb][1] * rl);
        ov.z = f2bf(o[qg][nb][2] * rl);
        ov.w = f2bf(o[qg][nb][3] * rl);
        *(ushort4*)&Ob[ob + nb * 16 + quad * 4] = ov;
      }
    }
  }
}

// ---------------------------------------------------------------------------
extern "C" void kernel_launch(void* const* d_in, const int* in_sizes, int n_in,
                              void* d_out, int out_size, void* d_ws, size_t ws_size,
                              hipStream_t stream) {
  const float* src   = (const float*)d_in[0];
  const float* Wq    = (const float*)d_in[1];
  const float* Wk    = (const float*)d_in[2];
  const float* Wv    = (const float*)d_in[3];
  const float* c_raw = (const float*)d_in[4];
  const float* Lp    = (const float*)d_in[5];
  const float* w1    = (const float*)d_in[6];
  const float* b1    = (const float*)d_in[7];
  const float* W2    = (const float*)d_in[8];
  const float* b2    = (const float*)d_in[9];
  const float* w3    = (const float*)d_in[10];
  const float* b3    = (const float*)d_in[11];
  const float* Wo    = (const float*)d_in[12];
  float* outp = (float*)d_out;

  const size_t SRC_E = 4194304;   // 8*1024*512
  const size_t W_E   = 262144;    // 512*512
  const size_t QKV_E = 4194304;   // 64*1024*64
  ushort_t* srcb = (ushort_t*)d_ws;
  ushort_t* Wqb  = srcb + SRC_E;
  ushort_t* Wkb  = Wqb + W_E;
  ushort_t* Wvb  = Wkb + W_E;
  ushort_t* Wob  = Wvb + W_E;
  ushort_t* Qb   = Wob + W_E;
  ushort_t* Kb   = Qb + QKV_E;
  ushort_t* Vtb  = Kb + QKV_E;    // V transposed: [b,h,kd,s]
  ushort_t* Obb  = Vtb + QKV_E;
  ushort_t* biaspre = Obb + QKV_E;                 // 8*136*128*32 ushorts
  float* numb  = (float*)(biaspre + (size_t)NHEAD * 136 * 128 * 32);
  float* rdenb = numb + NHEAD * S_LEN;
  float* gtabb = rdenb + NHEAD * S_LEN;

  // 1) bf16 convert + FIRE tables (independent, merged)
  hipLaunchKernelGGL(prep, dim3(7176), dim3(256), 0, stream,
                     src, Wq, Wk, Wv, Wo, srcb, Wqb, Wkb, Wvb, Wob,
                     c_raw, Lp, w1, b1, W2, b2, w3, b3, numb, rdenb, gtabb);
  // 2) QKV GEMM (3072 blocks, 64x64 tiles, z-fastest) + bias-pre (544 blocks)
  hipLaunchKernelGGL(gemm_bias, dim3(3616), dim3(256), 0, stream,
                     srcb, Wqb, Wkb, Wvb, (void*)Qb, (void*)Kb, (void*)Vtb,
                     1, 3072, numb, rdenb, gtabb, biaspre);
  // 3) attention (split-KV: 256 thr, 2 wave-pairs per block)
  hipLaunchKernelGGL(fire_attn_mfma, dim3(1024), dim3(256), 0, stream,
                     Qb, Kb, Vtb, biaspre, Obb);
  // 4) output projection (f32 out, 1024 blocks of 64x64)
  hipLaunchKernelGGL(gemm_bias, dim3(1024), dim3(256), 0, stream,
                     Obb, Wob, Wob, Wob, (void*)outp, (void*)outp, (void*)outp,
                     0, 1024, numb, rdenb, gtabb, biaspre);
}

// Round 8
// 157.786 us; speedup vs baseline: 1.1628x; 1.0171x over previous
//
#include <hip/hip_runtime.h>
#include <math.h>

#define S_LEN 1024
#define NHEAD 8
#define BATCH 8
#define KDIM  64
#define HID   32
#define NT    2048
#define LOG2E 1.4426950408889634f
#define TRI(q) ((q) * ((q) + 1) / 2)
// key-order bit-shuffle: m=[nb1 nb0 q1 q0 r1 r0] -> key=[nb1 q1 q0 nb0 r1 r0]
#define PERM(m) (((m) & 0x20) | (((m) & 0x0C) << 1) | (((m) & 0x10) >> 2) | ((m) & 3))
// LDS column swizzle key per row (3 bits, conflict-free for K(perm) and V reads)
#define SWZ(row) (((((row) >> 3) & 1) << 2) | ((row) & 3))

typedef __attribute__((ext_vector_type(8))) short bf16x8;
typedef __attribute__((ext_vector_type(4))) float f32x4;
typedef unsigned short ushort_t;

__device__ inline ushort_t f2bf(float f) {
  union { float f; unsigned u; } v; v.f = f;
  unsigned u = v.u;
  return (ushort_t)((u + 0x7FFFu + ((u >> 16) & 1u)) >> 16);
}
__device__ inline float bf2f(ushort_t u) {
  union { unsigned x; float f; } v; v.x = ((unsigned)u) << 16; return v.f;
}
__device__ inline unsigned cvtpk_bf16(float lo, float hi) {
  unsigned r;
  asm("v_cvt_pk_bf16_f32 %0, %1, %2" : "=v"(r) : "v"(lo), "v"(hi));
  return r;
}

// async global->LDS 16B: lane's LDS dest = lds_base + lane*16 (wave-uniform base)
__device__ inline void gl_lds16(const ushort_t* g, ushort_t* l) {
  __builtin_amdgcn_global_load_lds(
      (const __attribute__((address_space(1))) unsigned int*)g,
      (__attribute__((address_space(3))) unsigned int*)l, 16, 0, 0);
}

// ---------------------------------------------------------------------------
// Kernel 1: prep = to_bf16 (blocks 0..5119) + fire_tables (blocks 5120..7175).
// Q weights pre-scaled by (1/sqrt(KD)) * log2e and the FIRE bias table by
// log2e so attention softmax uses bare v_exp_f32 (exp2) with no per-value mul.
// ---------------------------------------------------------------------------
__global__ __launch_bounds__(256) void prep(
    const float* __restrict__ s, const float* __restrict__ wq,
    const float* __restrict__ wk, const float* __restrict__ wv,
    const float* __restrict__ wo,
    ushort_t* __restrict__ sb, ushort_t* __restrict__ wqb,
    ushort_t* __restrict__ wkb, ushort_t* __restrict__ wvb,
    ushort_t* __restrict__ wob,
    const float* __restrict__ c_raw, const float* __restrict__ Lp,
    const float* __restrict__ w1, const float* __restrict__ b1,
    const float* __restrict__ W2, const float* __restrict__ b2,
    const float* __restrict__ w3, const float* __restrict__ b3,
    float* __restrict__ num_g, float* __restrict__ rden_g,
    float* __restrict__ gtab_g) {
  __shared__ float h1s[8][33];
  const int bx = blockIdx.x;
  const int tid = threadIdx.x;
  if (bx < 5120) {
    const float* src; ushort_t* dst; int base; float scale = 1.0f;
    if (bx < 4096)      { src = s;  dst = sb;  base = bx; }
    else if (bx < 4352) { src = wq; dst = wqb; base = bx - 4096; scale = 0.125f * LOG2E; }
    else if (bx < 4608) { src = wk; dst = wkb; base = bx - 4352; }
    else if (bx < 4864) { src = wv; dst = wvb; base = bx - 4608; }
    else                { src = wo; dst = wob; base = bx - 4864; }
    const int i = (base * 256 + tid) * 4;
    float4 v = *(const float4*)&src[i];
    ushort4 o;
    o.x = f2bf(v.x * scale); o.y = f2bf(v.y * scale);
    o.z = f2bf(v.z * scale); o.w = f2bf(v.w * scale);
    *(ushort4*)&dst[i] = o;
  } else {
    const int idx = bx - 5120;
    const int h = idx / 257;
    const int xb = idx % 257;
    const float cr = c_raw[h];
    const float c = (cr > 20.f) ? cr : log1pf(expf(cr));
    const int gid = xb * 256 + tid;
    if (gid < S_LEN) {
      num_g[h * S_LEN + gid] = log1pf(c * (float)gid);
      rden_g[h * S_LEN + gid] = 1.0f / log1pf(c * fmaxf(Lp[h], (float)(gid + 1)));
    }
    const int pl = tid >> 5;             // point-local 0..7
    const int j = tid & 31;              // hidden dim
    const int pt = xb * 8 + pl;
    const float x = (float)pt * (1.0f / NT);
    float v = x * w1[h * HID + j] + b1[h * HID + j];
    h1s[pl][j] = 0.5f * v * (1.0f + erff(v * 0.70710678118f));
    __syncthreads();
    float sm = b2[h * HID + j];
    const float* w2r = W2 + ((size_t)(h * HID + j)) * HID;
    #pragma unroll
    for (int k = 0; k < HID; ++k) sm += w2r[k] * h1s[pl][k];
    float g = 0.5f * sm * (1.0f + erff(sm * 0.70710678118f));
    float y = w3[h * HID + j] * g;
    #pragma unroll
    for (int off = 1; off < 32; off <<= 1) y += __shfl_xor(y, off);
    if (j == 0 && pt <= NT) gtab_g[h * (NT + 1) + pt] = (y + b3[h]) * LOG2E;
  }
}

// ---------------------------------------------------------------------------
// Z-FUSED QKV tile (R8): one block computes Q, K, V for its 64x64 (m0,n0)
// tile from a SINGLE A staging. LDS 32 KB = A(8K) + Wq/Wk/Wv(24K), acc[3][4],
// 24 MFMA per K-step. vs 3 separate blocks: A staging traffic /3, per-step
// compute density x3 (hides the barrier-drain latency R5's counters exposed:
// MfmaUtil 8.5%, VALUBusy 13%, occupancy 35% -> all pipes idle), and 3x fewer
// serial 8-step barrier chains.
// ---------------------------------------------------------------------------
__device__ __forceinline__ void qkv_tile(
    ushort_t* sAB, const ushort_t* __restrict__ A,
    const ushort_t* __restrict__ Wq_, const ushort_t* __restrict__ Wk_,
    const ushort_t* __restrict__ Wv_,
    ushort_t* __restrict__ Qo, ushort_t* __restrict__ Ko,
    ushort_t* __restrict__ Vto, int m0, int n0, int tid) {
  ushort_t* sA = sAB;                  // 64x64 bf16 = 8 KB
  ushort_t* sW = sAB + 4096;           // 3 x 8 KB, z-major
  const int lane = tid & 63, w = tid >> 6, quad = lane >> 4, l16 = lane & 15;
  f32x4 acc[3][4];
  #pragma unroll
  for (int z = 0; z < 3; ++z)
    #pragma unroll
    for (int nb = 0; nb < 4; ++nb) acc[z][nb] = (f32x4)0.0f;

  const int r8 = lane >> 3;          // row within 8-row staging group
  const int gc = (lane & 7) ^ r8;    // swizzled source chunk for this lane
  const int sw = l16 & 7;            // frag-read swizzle key
  const ushort_t* Wz[3] = {Wq_, Wk_, Wv_};

  for (int kt = 0; kt < 512; kt += 64) {
    __syncthreads();
    #pragma unroll
    for (int j = 0; j < 2; ++j) {
      const int row = w * 16 + j * 8 + r8;
      gl_lds16(&A[(size_t)(m0 + row) * 512 + kt + gc * 8], &sA[(w * 16 + j * 8) * 64]);
      #pragma unroll
      for (int z = 0; z < 3; ++z)
        gl_lds16(&Wz[z][(size_t)(n0 + row) * 512 + kt + gc * 8],
                 &sW[z * 4096 + (w * 16 + j * 8) * 64]);
    }
    __syncthreads();
    #pragma unroll
    for (int ks = 0; ks < 2; ++ks) {
      const int off = ((ks * 4 + quad) ^ sw) * 8;
      bf16x8 af = *(const bf16x8*)&sA[(w * 16 + l16) * 64 + off];
      #pragma unroll
      for (int z = 0; z < 3; ++z)
        #pragma unroll
        for (int nb = 0; nb < 4; ++nb) {
          bf16x8 wf = *(const bf16x8*)&sW[z * 4096 + (nb * 16 + l16) * 64 + off];
          acc[z][nb] = __builtin_amdgcn_mfma_f32_16x16x32_bf16(af, wf, acc[z][nb], 0, 0, 0);
        }
    }
  }

  // ---- epilogue. z=0 (Q), z=1 (K): bf16 scatter [b,h,s,kd] (no LDS).
  const int bb = m0 >> 10, sbase = m0 & 1023;
  #pragma unroll
  for (int z = 0; z < 2; ++z) {
    ushort_t* outp = z ? Ko : Qo;
    #pragma unroll
    for (int nb = 0; nb < 4; ++nb)
      #pragma unroll
      for (int r = 0; r < 4; ++r) {
        int m = m0 + w * 16 + quad * 4 + r;
        int n = n0 + nb * 16 + l16;
        int ss = m & 1023, hh = n >> 6, kd = n & 63;
        outp[(((size_t)(bb * NHEAD + hh)) * S_LEN + ss) * KDIM + kd] = f2bf(acc[z][nb][r]);
      }
  }
  // z=2 (V): V^T via LDS transpose (XOR-swizzled [n][m]) -> [b,h,kd,s]
  __syncthreads();
  #pragma unroll
  for (int nb = 0; nb < 4; ++nb)
    #pragma unroll
    for (int r = 0; r < 4; ++r) {
      int nl = nb * 16 + l16;
      int ml = w * 16 + quad * 4 + r;
      sAB[nl * 64 + (((ml >> 3) ^ (nl & 7)) * 8) + (ml & 7)] = f2bf(acc[2][nb][r]);
    }
  __syncthreads();
  const int nl = tid >> 2, seg = tid & 3;
  const int ng = n0 + nl, hh = ng >> 6, kd = ng & 63;
  ushort_t* vout = Vto + (((size_t)(bb * NHEAD + hh)) * KDIM + kd) * S_LEN;
  #pragma unroll
  for (int c2 = 0; c2 < 2; ++c2) {
    int mc = seg * 2 + c2;
    bf16x8 vr = *(bf16x8*)&sAB[nl * 64 + ((mc ^ (nl & 7)) * 8)];
    *(bf16x8*)&vout[sbase + mc * 8] = vr;
  }
}

// ---------------------------------------------------------------------------
// Plain GEMM tile (out-proj): C = A(Mx512 bf16) * W^T, 64x64 tile, 4 waves,
// BK=64, single-buffer global_load_lds staging. mode 0: f32 out.
// ---------------------------------------------------------------------------
__device__ __forceinline__ void gemm_tile(
    ushort_t* sAB, const ushort_t* __restrict__ A, const ushort_t* __restrict__ Wp,
    float* __restrict__ outp, int m0, int n0, int tid) {
  ushort_t* sA = sAB;            // 64x64
  ushort_t* sB = sAB + 4096;
  const int lane = tid & 63, w = tid >> 6, quad = lane >> 4, l16 = lane & 15;
  f32x4 acc[4];
  #pragma unroll
  for (int nb = 0; nb < 4; ++nb) acc[nb] = (f32x4)0.0f;

  const int r8 = lane >> 3;
  const int gc = (lane & 7) ^ r8;
  const int sw = l16 & 7;

  for (int kt = 0; kt < 512; kt += 64) {
    __syncthreads();
    #pragma unroll
    for (int j = 0; j < 2; ++j) {
      const int row = w * 16 + j * 8 + r8;
      gl_lds16(&A[(size_t)(m0 + row) * 512 + kt + gc * 8], &sA[(w * 16 + j * 8) * 64]);
      gl_lds16(&Wp[(size_t)(n0 + row) * 512 + kt + gc * 8], &sB[(w * 16 + j * 8) * 64]);
    }
    __syncthreads();
    #pragma unroll
    for (int ks = 0; ks < 2; ++ks) {
      const int off = ((ks * 4 + quad) ^ sw) * 8;
      bf16x8 af = *(bf16x8*)&sA[(w * 16 + l16) * 64 + off];
      #pragma unroll
      for (int nb = 0; nb < 4; ++nb) {
        bf16x8 bfr = *(bf16x8*)&sB[(nb * 16 + l16) * 64 + off];
        acc[nb] = __builtin_amdgcn_mfma_f32_16x16x32_bf16(af, bfr, acc[nb], 0, 0, 0);
      }
    }
  }
  #pragma unroll
  for (int nb = 0; nb < 4; ++nb) {
    #pragma unroll
    for (int r = 0; r < 4; ++r) {
      int m = m0 + w * 16 + quad * 4 + r;
      int n = n0 + nb * 16 + l16;
      outp[(size_t)m * 512 + n] = acc[nb][r];
    }
  }
}

// ---------------------------------------------------------------------------
// Kernel 2/4: gemm_bias. scatter=1: blocks < nGemm are z-fused QKV tiles
// (1024 blocks, m0=(tile&127)*64, n0=(tile>>7)*64); blocks >= nGemm are
// bias-pre. scatter=0: out-proj (f32 out).
// ---------------------------------------------------------------------------
__global__ __launch_bounds__(256) void gemm_bias(
    const ushort_t* __restrict__ A,
    const ushort_t* __restrict__ W0, const ushort_t* __restrict__ W1,
    const ushort_t* __restrict__ W2w,
    void* __restrict__ out0, void* __restrict__ out1, void* __restrict__ out2,
    int scatter, int nGemm,
    const float* __restrict__ num_g, const float* __restrict__ rden_g,
    const float* __restrict__ gtab_g, ushort_t* __restrict__ biaspre) {
  __shared__ __align__(16) ushort_t sAB[16384];   // 32 KB
  const int tid = threadIdx.x;
  if ((int)blockIdx.x < nGemm) {
    const int tile = blockIdx.x;
    const int m0 = (tile & 127) * 64;
    const int n0 = (tile >> 7) * 64;
    if (scatter) {
      qkv_tile(sAB, A, W0, W1, W2w, (ushort_t*)out0, (ushort_t*)out1,
               (ushort_t*)out2, m0, n0, tid);
    } else {
      gemm_tile(sAB, A, W0, (float*)out0, m0, n0, tid);
    }
  } else {
    const int idx = blockIdx.x - nGemm;      // 0..543
    const int h = idx / 68;
    const int pair = idx % 68;
    float* gtab_s = (float*)sAB;             // 2049 floats
    float* num_s = gtab_s + 2052;            // 1024 floats
    float* rden_s = num_s + 1024;            // [2][64]  (total ~12.9 KB < 32 KB)
    for (int i = tid; i <= NT; i += 256) gtab_s[i] = gtab_g[h * (NT + 1) + i];
    for (int i = tid; i < S_LEN; i += 256) num_s[i] = num_g[h * S_LEN + i];
    const int sub = tid >> 7, tid2 = tid & 127;
    const int tileIdx = pair * 2 + sub;
    int qt = 0;
    while (TRI(qt + 1) <= tileIdx) ++qt;
    const int t = tileIdx - TRI(qt);
    if (tid2 < 64) rden_s[sub * 64 + tid2] = rden_g[h * S_LEN + qt * 64 + tid2];
    __syncthreads();
    const int w = tid2 >> 6, lane = tid2 & 63, quad = lane >> 4, l16 = lane & 15;
    ushort_t vals[32];
    #pragma unroll
    for (int qg = 0; qg < 2; ++qg) {
      const int iloc = w * 32 + qg * 16 + l16;
      const int i = qt * 64 + iloc;
      const float rden = rden_s[sub * 64 + iloc];
      #pragma unroll
      for (int nb = 0; nb < 4; ++nb)
        #pragma unroll
        for (int r = 0; r < 4; ++r) {
          const int m = nb * 16 + quad * 4 + r;
          const int j = t * 64 + PERM(m);
          ushort_t out;
          if (j > i) {
            out = 0xFF80;  // bf16 -inf (causal)
          } else {
            const int d = i - j;
            float x = num_s[d] * rden;       // in [0,1)
            float tf = x * (float)NT;
            int it = (int)tf; it = it < (NT - 1) ? it : (NT - 1);
            float fr = tf - (float)it;
            float ga = gtab_s[it];
            out = f2bf(ga + (gtab_s[it + 1] - ga) * fr);
          }
          vals[qg * 16 + nb * 4 + r] = out;
        }
    }
    ushort_t* dst = &biaspre[((size_t)(h * 136 + tileIdx) * 128 + tid2) * 32];
    uint4 u[2];
    #pragma unroll
    for (int half = 0; half < 2; ++half) {
      #pragma unroll
      for (int v = 0; v < 8; ++v) ((ushort_t*)&u[0])[v] = vals[half * 16 + v];
      #pragma unroll
      for (int v = 0; v < 8; ++v) ((ushort_t*)&u[1])[v] = vals[half * 16 + 8 + v];
      *(uint4*)(dst + half * 16) = u[0];
      *(uint4*)(dst + half * 16 + 8) = u[1];
    }
  }
}

// ---------------------------------------------------------------------------
// Kernel 3: transposed MFMA causal flash attention, SPLIT-KV (R7 config,
// measured -7 us). 1024 blocks x 256 thr = 2 wave-pairs; pair 0 tiles
// [0,hA), pair 1 [hA,qt]; per-pair 16 KB K/V LDS; in-block (o,l) combine.
// S^T = K.Q^T with PERM'd key order; P^T fragments register-local.
// Softmax: exp2-folded + v_cvt_pk_bf16_f32 packing.
// ---------------------------------------------------------------------------
__global__ __launch_bounds__(256) void fire_attn_mfma(
    const ushort_t* __restrict__ Qg, const ushort_t* __restrict__ Kg,
    const ushort_t* __restrict__ Vtg, const ushort_t* __restrict__ biaspre,
    ushort_t* __restrict__ Ob) {
  __shared__ __align__(16) ushort_t sKV[16384];  // K: pair*4096, V: 8192+pair*4096
  const int tid = threadIdx.x;
  const int lane = tid & 63, w = tid >> 6;
  const int pair = w >> 1, wq = w & 1;           // pair 0/1; wave-within-pair
  const int quad = lane >> 4, l16 = lane & 15;
  const int g = blockIdx.x >> 6;
  const int qt = (g < 8) ? (15 - g) : (g - 8);
  const int bh = blockIdx.x & 63, h = bh & 7, b = bh >> 3;
  const int tid2 = wq * 64 + lane;               // 0..127 within pair

  bf16x8 q[2][2];
  {
    const size_t qb = (size_t)bh * S_LEN + qt * 64 + wq * 32;
    #pragma unroll
    for (int qg = 0; qg < 2; ++qg)
      #pragma unroll
      for (int ks = 0; ks < 2; ++ks)
        q[qg][ks] = *(const bf16x8*)&Qg[(qb + qg * 16 + l16) * KDIM + ks * 32 + quad * 8];
  }

  const size_t kb = (size_t)bh * S_LEN * KDIM;
  const ushort_t* bptr = &biaspre[((size_t)(h * 136 + TRI(qt)) * 128 + tid2) * 32];
  const int srow8 = lane >> 3;   // staging row-within-group
  const int sc = lane & 7;       // staging chunk

  ushort_t* Kp = sKV + pair * 4096;
  ushort_t* Vp = sKV + 8192 + pair * 4096;

  auto stageKV = [&](int t) {
    #pragma unroll
    for (int j = 0; j < 4; ++j) {
      const int row = (wq * 4 + j) * 8 + srow8;
      const int cc = sc ^ SWZ(row);
      gl_lds16(&Kg[kb + (size_t)(t * 64 + row) * 64 + cc * 8], &Kp[(wq * 4 + j) * 512]);
      gl_lds16(&Vtg[kb + (size_t)row * 1024 + t * 64 + cc * 8], &Vp[(wq * 4 + j) * 512]);
    }
  };

  f32x4 o[2][4];
  float ll[2] = {0.f, 0.f};
  #pragma unroll
  for (int qg = 0; qg < 2; ++qg)
    #pragma unroll
    for (int nb = 0; nb < 4; ++nb) o[qg][nb] = (f32x4)0.0f;

  const int hA = (qt + 2) >> 1;        // pair 0 tile count (>= pair 1's)
  for (int it = 0; it < hA; ++it) {
    const int t = pair ? (hA + it) : it;
    const bool act = (!pair) || (t <= qt);   // wave-uniform predicate
    if (act) stageKV(t);
    __syncthreads();                   // staging landed (both pairs)
    if (act) {
      uint4 bb0 = ((const uint4*)(bptr + (size_t)t * 4096))[0];
      uint4 bb1 = ((const uint4*)(bptr + (size_t)t * 4096))[1];
      uint4 bb2 = ((const uint4*)(bptr + (size_t)t * 4096))[2];
      uint4 bb3 = ((const uint4*)(bptr + (size_t)t * 4096))[3];

      // ---- S^T = K . Q^T  (keys in PERM order on the m-dim)
      f32x4 s[2][4];
      #pragma unroll
      for (int qg = 0; qg < 2; ++qg)
        #pragma unroll
        for (int nb = 0; nb < 4; ++nb) s[qg][nb] = (f32x4)0.0f;
      #pragma unroll
      for (int ks = 0; ks < 2; ++ks) {
        #pragma unroll
        for (int nb = 0; nb < 4; ++nb) {
          const int rk = PERM(nb * 16 + l16);
          bf16x8 ak = *(const bf16x8*)&Kp[rk * 64 + (((ks * 4 + quad) ^ SWZ(rk)) * 8)];
          #pragma unroll
          for (int qg = 0; qg < 2; ++qg)
            s[qg][nb] = __builtin_amdgcn_mfma_f32_16x16x32_bf16(ak, q[qg][ks], s[qg][nb], 0, 0, 0);
        }
      }

      // ---- P = exp2(S + bias); no-max softmax; l per-lane
      unsigned pk[2][4][2];
      #pragma unroll
      for (int qg = 0; qg < 2; ++qg) {
        #pragma unroll
        for (int nb = 0; nb < 4; ++nb) {
          const int v = qg * 16 + nb * 4;
          const uint4& bq = (v < 8) ? bb0 : (v < 16) ? bb1 : (v < 24) ? bb2 : bb3;
          const ushort_t* bu = (const ushort_t*)&bq;
          float p0 = __builtin_amdgcn_exp2f(s[qg][nb][0] + bf2f(bu[(v + 0) & 7]));
          float p1 = __builtin_amdgcn_exp2f(s[qg][nb][1] + bf2f(bu[(v + 1) & 7]));
          float p2 = __builtin_amdgcn_exp2f(s[qg][nb][2] + bf2f(bu[(v + 2) & 7]));
          float p3 = __builtin_amdgcn_exp2f(s[qg][nb][3] + bf2f(bu[(v + 3) & 7]));
          ll[qg] += (p0 + p1) + (p2 + p3);
          pk[qg][nb][0] = cvtpk_bf16(p0, p1);
          pk[qg][nb][1] = cvtpk_bf16(p2, p3);
        }
      }

      // ---- O^T += V^T . P^T (P^T B-frags register-local thanks to PERM)
      #pragma unroll
      for (int ks = 0; ks < 2; ++ks) {
        bf16x8 pf[2];
        #pragma unroll
        for (int qg = 0; qg < 2; ++qg) {
          union { bf16x8 v; unsigned u[4]; } pkx;
          pkx.u[0] = pk[qg][2 * ks][0];
          pkx.u[1] = pk[qg][2 * ks][1];
          pkx.u[2] = pk[qg][2 * ks + 1][0];
          pkx.u[3] = pk[qg][2 * ks + 1][1];
          pf[qg] = pkx.v;
        }
        #pragma unroll
        for (int nb = 0; nb < 4; ++nb) {
          const int rv = nb * 16 + l16;
          bf16x8 av = *(const bf16x8*)&Vp[rv * 64 + (((ks * 4 + quad) ^ SWZ(rv)) * 8)];
          #pragma unroll
          for (int qg = 0; qg < 2; ++qg)
            o[qg][nb] = __builtin_amdgcn_mfma_f32_16x16x32_bf16(av, pf[qg], o[qg][nb], 0, 0, 0);
        }
      }
    }
    __syncthreads();                   // reads done before buffer reuse
  }

  // ---- pair combine via LDS (34 floats/thread-slot; 2-way bank alias = free)
  float* cb = (float*)sKV;
  if (pair == 1) {
    float* my = cb + tid2 * 34;
    #pragma unroll
    for (int qg = 0; qg < 2; ++qg)
      #pragma unroll
      for (int nb = 0; nb < 4; ++nb)
        #pragma unroll
        for (int r = 0; r < 4; ++r) my[qg * 16 + nb * 4 + r] = o[qg][nb][r];
    my[32] = ll[0]; my[33] = ll[1];
  }
  __syncthreads();
  if (pair == 0) {
    const float* pb = cb + tid2 * 34;
    #pragma unroll
    for (int qg = 0; qg < 2; ++qg)
      #pragma unroll
      for (int nb = 0; nb < 4; ++nb)
        #pragma unroll
        for (int r = 0; r < 4; ++r) o[qg][nb][r] += pb[qg * 16 + nb * 4 + r];
    ll[0] += pb[32]; ll[1] += pb[33];

    #pragma unroll
    for (int qg = 0; qg < 2; ++qg) {
      float rs = ll[qg];
      rs += __shfl_xor(rs, 16);
      rs += __shfl_xor(rs, 32);
      const float rl = 1.0f / rs;
      const size_t ob = ((size_t)(b * S_LEN + qt * 64 + wq * 32 + qg * 16 + l16)) * 512 + h * KDIM;
      #pragma unroll
      for (int nb = 0; nb < 4; ++nb) {
        ushort4 ov;
        ov.x = f2bf(o[qg][nb][0] * rl);
        ov.y = f2bf(o[qg][nb][1] * rl);
        ov.z = f2bf(o[qg][nb][2] * rl);
        ov.w = f2bf(o[qg][nb][3] * rl);
        *(ushort4*)&Ob[ob + nb * 16 + quad * 4] = ov;
      }
    }
  }
}

// ---------------------------------------------------------------------------
extern "C" void kernel_launch(void* const* d_in, const int* in_sizes, int n_in,
                              void* d_out, int out_size, void* d_ws, size_t ws_size,
                              hipStream_t stream) {
  const float* src   = (const float*)d_in[0];
  const float* Wq    = (const float*)d_in[1];
  const float* Wk    = (const float*)d_in[2];
  const float* Wv    = (const float*)d_in[3];
  const float* c_raw = (const float*)d_in[4];
  const float* Lp    = (const float*)d_in[5];
  const float* w1    = (const float*)d_in[6];
  const float* b1    = (const float*)d_in[7];
  const float* W2    = (const float*)d_in[8];
  const float* b2    = (const float*)d_in[9];
  const float* w3    = (const float*)d_in[10];
  const float* b3    = (const float*)d_in[11];
  const float* Wo    = (const float*)d_in[12];
  float* outp = (float*)d_out;

  const size_t SRC_E = 4194304;   // 8*1024*512
  const size_t W_E   = 262144;    // 512*512
  const size_t QKV_E = 4194304;   // 64*1024*64
  ushort_t* srcb = (ushort_t*)d_ws;
  ushort_t* Wqb  = srcb + SRC_E;
  ushort_t* Wkb  = Wqb + W_E;
  ushort_t* Wvb  = Wkb + W_E;
  ushort_t* Wob  = Wvb + W_E;
  ushort_t* Qb   = Wob + W_E;
  ushort_t* Kb   = Qb + QKV_E;
  ushort_t* Vtb  = Kb + QKV_E;    // V transposed: [b,h,kd,s]
  ushort_t* Obb  = Vtb + QKV_E;
  ushort_t* biaspre = Obb + QKV_E;                 // 8*136*128*32 ushorts
  float* numb  = (float*)(biaspre + (size_t)NHEAD * 136 * 128 * 32);
  float* rdenb = numb + NHEAD * S_LEN;
  float* gtabb = rdenb + NHEAD * S_LEN;

  // 1) bf16 convert + FIRE tables (independent, merged)
  hipLaunchKernelGGL(prep, dim3(7176), dim3(256), 0, stream,
                     src, Wq, Wk, Wv, Wo, srcb, Wqb, Wkb, Wvb, Wob,
                     c_raw, Lp, w1, b1, W2, b2, w3, b3, numb, rdenb, gtabb);
  // 2) z-fused QKV GEMM (1024 blocks) + bias-pre (544 blocks)
  hipLaunchKernelGGL(gemm_bias, dim3(1568), dim3(256), 0, stream,
                     srcb, Wqb, Wkb, Wvb, (void*)Qb, (void*)Kb, (void*)Vtb,
                     1, 1024, numb, rdenb, gtabb, biaspre);
  // 3) attention (split-KV: 256 thr, 2 wave-pairs per block)
  hipLaunchKernelGGL(fire_attn_mfma, dim3(1024), dim3(256), 0, stream,
                     Qb, Kb, Vtb, biaspre, Obb);
  // 4) output projection (f32 out, 1024 blocks of 64x64)
  hipLaunchKernelGGL(gemm_bias, dim3(1024), dim3(256), 0, stream,
                     Obb, Wob, Wob, Wob, (void*)outp, (void*)outp, (void*)outp,
                     0, 1024, numb, rdenb, gtabb, biaspre);
}